// Round 4
// baseline (358.565 us; speedup 1.0000x reference)
//
#include <hip/hip_runtime.h>

typedef __attribute__((ext_vector_type(8))) short short8;
typedef __attribute__((ext_vector_type(4))) float floatx4;

constexpr int DIM   = 128;   // dim_in == dim_out
constexpr int NB    = 4;     // bases
constexpr int NR    = 8;     // relations
constexpr int BROWS = 512;   // rows per sort bucket
constexpr int BCAP  = 16384; // fixed bucket capacity (mean 8192, +90 sigma)

static __device__ __forceinline__ unsigned short f2bf(float f) {
    unsigned int u = __float_as_uint(f);
    u += 0x7FFFu + ((u >> 16) & 1u);
    return (unsigned short)(u >> 16);
}
static __device__ __forceinline__ float bf_lo(unsigned int h) {
    return __uint_as_float(h << 16);
}
static __device__ __forceinline__ float bf_hi(unsigned int h) {
    return __uint_as_float(h & 0xFFFF0000u);
}

// ---------------------------------------------------------------------------
// Vfrag[b][ot][ks][lane][j] = V[b][k][o], k=ks*32+(lane>>4)*8+j, o=ot*16+(lane&15)
// ---------------------------------------------------------------------------
__global__ __launch_bounds__(256) void build_vfrag(
    const float* __restrict__ V, unsigned short* __restrict__ VfragG)
{
    int idx  = blockIdx.x * 256 + threadIdx.x;   // 0 .. 8191
    int lane = idx & 63;
    int ks   = (idx >> 6) & 3;
    int ot   = (idx >> 8) & 7;
    int b    = idx >> 11;

    int o  = ot * 16 + (lane & 15);
    int kb = ks * 32 + (lane >> 4) * 8;

    short8 v;
#pragma unroll
    for (int j = 0; j < 8; ++j)
        v[j] = (short)f2bf(V[((size_t)b * DIM + kb + j) * DIM + o]);
    *reinterpret_cast<short8*>(VfragG + (size_t)idx * 8) = v;
}

// ---------------------------------------------------------------------------
// W_r fragments (fallback path only)
// ---------------------------------------------------------------------------
__global__ __launch_bounds__(256) void build_wfrag(
    const float* __restrict__ A, const float* __restrict__ V,
    unsigned short* __restrict__ Wfrag)
{
    int idx  = blockIdx.x * 256 + threadIdx.x;   // 0 .. 16383
    int lane = idx & 63;
    int ks   = (idx >> 6) & 3;
    int ot   = (idx >> 8) & 7;
    int r    = idx >> 11;

    int o     = ot * 16 + (lane & 15);
    int kbase = ks * 32 + (lane >> 4) * 8;

    float a0 = A[r * NB + 0], a1 = A[r * NB + 1];
    float a2 = A[r * NB + 2], a3 = A[r * NB + 3];

    short8 v;
#pragma unroll
    for (int j = 0; j < 8; ++j) {
        int k = kbase + j;
        float w = a0 * V[(0 * DIM + k) * DIM + o]
                + a1 * V[(1 * DIM + k) * DIM + o]
                + a2 * V[(2 * DIM + k) * DIM + o]
                + a3 * V[(3 * DIM + k) * DIM + o];
        v[j] = (short)f2bf(w);
    }
    *reinterpret_cast<short8*>(Wfrag + (size_t)idx * 8) = v;
}

// ---------------------------------------------------------------------------
// H (fp32) -> Hbf (bf16), row-major [Ne][128]
// ---------------------------------------------------------------------------
__global__ __launch_bounds__(256) void h_to_bf(
    const float* __restrict__ H, unsigned short* __restrict__ Hbf, int n8)
{
    int i = blockIdx.x * 256 + threadIdx.x;
    if (i >= n8) return;
    const float4* hp = reinterpret_cast<const float4*>(H) + (size_t)i * 2;
    float4 f0 = hp[0];
    float4 f1 = hp[1];
    short8 v;
    v[0] = (short)f2bf(f0.x); v[1] = (short)f2bf(f0.y);
    v[2] = (short)f2bf(f0.z); v[3] = (short)f2bf(f0.w);
    v[4] = (short)f2bf(f1.x); v[5] = (short)f2bf(f1.y);
    v[6] = (short)f2bf(f1.z); v[7] = (short)f2bf(f1.w);
    *reinterpret_cast<short8*>(Hbf + (size_t)i * 8) = v;
}

// ---------------------------------------------------------------------------
// Sort pass 1: scatter edges into fixed-capacity coarse buckets
// ---------------------------------------------------------------------------
__global__ __launch_bounds__(256) void bucket_scatter(
    const int* __restrict__ erow, const int* __restrict__ ecol,
    const float* __restrict__ eval, int* __restrict__ bcnt,
    int2* __restrict__ sorted1, int n, int E, int chunk)
{
    __shared__ int cnt[256];
    __shared__ int base[256];
    int t = threadIdx.x;
    cnt[t] = 0;
    __syncthreads();

    int s = blockIdx.x * chunk;
    int e = s + chunk; if (e > n) e = n;

    for (int i = s + t; i < e; i += 256)
        atomicAdd(&cnt[erow[i] >> 9], 1);
    __syncthreads();

    int c = cnt[t];
    base[t] = (c > 0) ? atomicAdd(&bcnt[t], c) : 0;
    cnt[t] = 0;
    __syncthreads();

    for (int i = s + t; i < e; i += 256) {
        int row = erow[i];
        int bkt = row >> 9;
        int rank = atomicAdd(&cnt[bkt], 1);
        int r = (int)((unsigned)i / (unsigned)E);
        int2 m;
        m.x = ((row & (BROWS - 1)) << 20) | (r << 17) | ecol[i];
        m.y = __float_as_int(eval[i]);
        sorted1[(size_t)bkt * BCAP + base[bkt] + rank] = m;
    }
}

// ---------------------------------------------------------------------------
// Exclusive scan over the 196 bucket counts (single block)
// ---------------------------------------------------------------------------
__global__ __launch_bounds__(256) void bucket_scan(
    const int* __restrict__ bcnt, int* __restrict__ bstart,
    int* __restrict__ rowStart, int nbuc, int Ne)
{
    __shared__ int sd[256];
    int t = threadIdx.x;
    int c = (t < nbuc) ? bcnt[t] : 0;
    sd[t] = c; __syncthreads();
#pragma unroll
    for (int off = 1; off < 256; off <<= 1) {
        int v = (t >= off) ? sd[t - off] : 0;
        __syncthreads();
        sd[t] += v;
        __syncthreads();
    }
    if (t < nbuc) bstart[t] = sd[t] - c;
    if (t == nbuc - 1) rowStart[Ne] = sd[t];
}

// ---------------------------------------------------------------------------
// Sort pass 2: one block per bucket; compacts to exact final positions.
// ---------------------------------------------------------------------------
__global__ __launch_bounds__(256) void bucket_sort(
    const int2* __restrict__ sorted1, const int* __restrict__ bcnt,
    const int* __restrict__ bstart, int* __restrict__ rowStart,
    int2* __restrict__ sorted, int Ne)
{
    __shared__ int hcnt[BROWS];
    __shared__ int hoff[BROWS];
    int b = blockIdx.x;
    int t = threadIdx.x;
    hcnt[t] = 0; hcnt[t + 256] = 0;
    __syncthreads();

    int n = bcnt[b];
    const int2* src = sorted1 + (size_t)b * BCAP;

    for (int i = t; i < n; i += 256)
        atomicAdd(&hcnt[(unsigned)src[i].x >> 20], 1);
    __syncthreads();

    if (t == 0) {
        int run = 0;
#pragma unroll 8
        for (int j = 0; j < BROWS; ++j) { hoff[j] = run; run += hcnt[j]; }
    }
    __syncthreads();

    int bs = bstart[b];
    int rs = b * BROWS;
    int nr = Ne - rs; if (nr > BROWS) nr = BROWS;
    for (int j = t; j < nr; j += 256)
        rowStart[rs + j] = bs + hoff[j];

    hcnt[t] = 0; hcnt[t + 256] = 0;
    __syncthreads();

    for (int i = t; i < n; i += 256) {
        int2 m = src[i];
        int lr = (unsigned)m.x >> 20;
        int pos = bs + hoff[lr] + atomicAdd(&hcnt[lr], 1);
        sorted[pos] = m;
    }
}

// ---------------------------------------------------------------------------
// K_A: basis aggregation. One wave per destination row.
// 8-edge unroll: 8 gathers in flight per wave (was 4) to cover gather
// latency (VALUBusy was 52% -> half the time was latency stall; VGPR was
// only 24 so the deeper unroll is free). Accumulation order per acc is
// unchanged -> bit-identical output.
// ---------------------------------------------------------------------------
__global__ __launch_bounds__(256) void agg_kernel(
    const unsigned short* __restrict__ Hbf,
    const int*  __restrict__ rowStart,
    const int2* __restrict__ sorted,
    const float* __restrict__ Aw,
    unsigned short* __restrict__ Agg, int Ne)
{
    int tid  = threadIdx.x;
    int wid  = __builtin_amdgcn_readfirstlane(blockIdx.x * 4 + (tid >> 6));
    if (wid >= Ne) return;
    int lane = tid & 63;

    int s = __builtin_amdgcn_readfirstlane(rowStart[wid]);
    int e = __builtin_amdgcn_readfirstlane(rowStart[wid + 1]);

    const float4* Af = reinterpret_cast<const float4*>(Aw);

    float2 acc[4];
#pragma unroll
    for (int b = 0; b < 4; ++b) { acc[b].x = 0.f; acc[b].y = 0.f; }

    int i = s;
    for (; i + 8 <= e; i += 8) {
        int kk[8];
        float vv[8];
        unsigned int hh[8];
#pragma unroll
        for (int u = 0; u < 8; ++u) {
            int2 m = sorted[i + u];
            kk[u] = __builtin_amdgcn_readfirstlane(m.x);
            vv[u] = __uint_as_float(__builtin_amdgcn_readfirstlane(m.y));
        }
#pragma unroll
        for (int u = 0; u < 8; ++u)
            hh[u] = reinterpret_cast<const unsigned int*>(
                Hbf + (size_t)(kk[u] & 0x1FFFF) * DIM)[lane];
#pragma unroll
        for (int u = 0; u < 8; ++u) {
            float4 a = Af[((unsigned)kk[u] >> 17) & 7];
            float hx = bf_lo(hh[u]), hy = bf_hi(hh[u]);
            float s0 = vv[u] * a.x, s1 = vv[u] * a.y;
            float s2 = vv[u] * a.z, s3 = vv[u] * a.w;
            acc[0].x += s0 * hx; acc[0].y += s0 * hy;
            acc[1].x += s1 * hx; acc[1].y += s1 * hy;
            acc[2].x += s2 * hx; acc[2].y += s2 * hy;
            acc[3].x += s3 * hx; acc[3].y += s3 * hy;
        }
    }
    for (; i < e; ++i) {
        int2 m = sorted[i];
        int k = __builtin_amdgcn_readfirstlane(m.x);
        float v = __uint_as_float(__builtin_amdgcn_readfirstlane(m.y));
        unsigned int h = reinterpret_cast<const unsigned int*>(
            Hbf + (size_t)(k & 0x1FFFF) * DIM)[lane];
        float4 a = Af[((unsigned)k >> 17) & 7];
        float hx = bf_lo(h), hy = bf_hi(h);
        float s0 = v * a.x, s1 = v * a.y, s2 = v * a.z, s3 = v * a.w;
        acc[0].x += s0 * hx; acc[0].y += s0 * hy;
        acc[1].x += s1 * hx; acc[1].y += s1 * hy;
        acc[2].x += s2 * hx; acc[2].y += s2 * hy;
        acc[3].x += s3 * hx; acc[3].y += s3 * hy;
    }

    unsigned short* arow = Agg + (size_t)wid * 512 + lane * 2;
#pragma unroll
    for (int b = 0; b < 4; ++b) {
        unsigned int pk = (unsigned int)f2bf(acc[b].x)
                        | ((unsigned int)f2bf(acc[b].y) << 16);
        *reinterpret_cast<unsigned int*>(arow + b * 128) = pk;
    }
}

// ---------------------------------------------------------------------------
// K_B: out = Agg @ V  (M=Ne, K=512, N=128), MFMA.
// Round-3 structure (512 thr, 64 KB LDS, XCD-paired halves) + basis-granular
// software pipeline: ping-pong bufA/bufB (4 short8 each, 32 VGPR total vs 64
// for the old bf[16]) -> load basis b+1 overlaps MFMA of basis b; at b=3 the
// NEXT tile's basis 0 is prefetched. Breaks the all-waves-lockstep convoy
// (load burst / stall / compute phases alternating with both pipes idle).
// No net register growth -> no spill risk (rounds 1-2 failure mode).
// ---------------------------------------------------------------------------
__global__ __launch_bounds__(512) void vgemm_kernel(
    const unsigned short* __restrict__ Agg,
    const unsigned short* __restrict__ VfragG,
    float* __restrict__ out, int Ne, int nTiles)
{
    __shared__ short8 ldsV[4096];   // [b][otl][ks][lane], 64 KB
    int half = (blockIdx.x >> 3) & 1;                       // XCD-paired
    int blk  = ((blockIdx.x >> 4) << 3) | (blockIdx.x & 7); // same %8 pair
    int nblk = gridDim.x >> 1;
    int tid  = threadIdx.x;

    for (int i = tid; i < 4096; i += 512) {
        int lane = i & 63, ks = (i >> 6) & 3, otl = (i >> 8) & 3, b = i >> 10;
        int gi = ((b * 8 + half * 4 + otl) * 4 + ks) * 64 + lane;
        ldsV[i] = reinterpret_cast<const short8*>(VfragG)[gi];
    }
    __syncthreads();

    int wave = tid >> 6;
    int lane = tid & 63;
    int quad = lane >> 4, l15 = lane & 15;

    int wgid = blk * 8 + wave;
    int nw   = nblk * 8;

    if (wgid >= nTiles) return;

    const short8* AggV = reinterpret_cast<const short8*>(Agg);

    short8 bufA[4], bufB[4];

    const short8* bp;
    {
        int node = wgid * 16 + l15;
        int rd   = node < Ne ? node : Ne - 1;
        bp = AggV + (size_t)rd * 64 + quad;
    }
#pragma unroll
    for (int ks = 0; ks < 4; ++ks) bufA[ks] = bp[0 * 16 + ks * 4];

    int tile = wgid;
    for (;;) {
        int node = tile * 16 + l15;

        floatx4 acc[4];
#pragma unroll
        for (int o = 0; o < 4; ++o) acc[o] = (floatx4){0.f, 0.f, 0.f, 0.f};

        // ---- basis 0: load b1 -> bufB, MFMA bufA
#pragma unroll
        for (int ks = 0; ks < 4; ++ks) bufB[ks] = bp[1 * 16 + ks * 4];
#pragma unroll
        for (int ks = 0; ks < 4; ++ks)
#pragma unroll
            for (int otl = 0; otl < 4; ++otl)
                acc[otl] = __builtin_amdgcn_mfma_f32_16x16x32_bf16(
                    ldsV[((0 * 4 + otl) * 4 + ks) * 64 + lane],
                    bufA[ks], acc[otl], 0, 0, 0);

        // ---- basis 1: load b2 -> bufA, MFMA bufB
#pragma unroll
        for (int ks = 0; ks < 4; ++ks) bufA[ks] = bp[2 * 16 + ks * 4];
#pragma unroll
        for (int ks = 0; ks < 4; ++ks)
#pragma unroll
            for (int otl = 0; otl < 4; ++otl)
                acc[otl] = __builtin_amdgcn_mfma_f32_16x16x32_bf16(
                    ldsV[((1 * 4 + otl) * 4 + ks) * 64 + lane],
                    bufB[ks], acc[otl], 0, 0, 0);

        // ---- basis 2: load b3 -> bufB, MFMA bufA
#pragma unroll
        for (int ks = 0; ks < 4; ++ks) bufB[ks] = bp[3 * 16 + ks * 4];
#pragma unroll
        for (int ks = 0; ks < 4; ++ks)
#pragma unroll
            for (int otl = 0; otl < 4; ++otl)
                acc[otl] = __builtin_amdgcn_mfma_f32_16x16x32_bf16(
                    ldsV[((2 * 4 + otl) * 4 + ks) * 64 + lane],
                    bufA[ks], acc[otl], 0, 0, 0);

        // ---- basis 3: prefetch next tile's b0 -> bufA, MFMA bufB
        int tn = tile + nw;
        const short8* bpn = bp;
        if (tn < nTiles) {
            int noden = tn * 16 + l15;
            int rdn   = noden < Ne ? noden : Ne - 1;
            bpn = AggV + (size_t)rdn * 64 + quad;
#pragma unroll
            for (int ks = 0; ks < 4; ++ks) bufA[ks] = bpn[0 * 16 + ks * 4];
        }
#pragma unroll
        for (int ks = 0; ks < 4; ++ks)
#pragma unroll
            for (int otl = 0; otl < 4; ++otl)
                acc[otl] = __builtin_amdgcn_mfma_f32_16x16x32_bf16(
                    ldsV[((3 * 4 + otl) * 4 + ks) * 64 + lane],
                    bufB[ks], acc[otl], 0, 0, 0);

        if (node < Ne) {
            float* orow = out + (size_t)node * DIM + half * 64;
#pragma unroll
            for (int otl = 0; otl < 4; ++otl) {
                float4 st;
                st.x = acc[otl][0]; st.y = acc[otl][1];
                st.z = acc[otl][2]; st.w = acc[otl][3];
                *reinterpret_cast<float4*>(orow + otl * 16 + quad * 4) = st;
            }
        }

        if (tn >= nTiles) break;
        tile = tn;
        bp   = bpn;
    }
}

// ---------------------------------------------------------------------------
// Fallback (ws too small): round-2 atomic kernel
// ---------------------------------------------------------------------------
__global__ __launch_bounds__(256) void rgcn_main(
    const unsigned short* __restrict__ Hbf,
    const unsigned short* __restrict__ Wfrag,
    const int*   __restrict__ erow,
    const int*   __restrict__ ecol,
    const float* __restrict__ eval,
    float*       __restrict__ out,
    int E, int groups_per_rel, int waves_per_rel)
{
    int wid  = blockIdx.x * 4 + (threadIdx.x >> 6);
    int lane = threadIdx.x & 63;
    int r    = wid & 7;
    int wr   = wid >> 3;
    int quad = lane >> 4;
    int l15  = lane & 15;

    short8 b[8][4];
    {
        const short8* wp = reinterpret_cast<const short8*>(
            Wfrag + (size_t)r * 16384);
#pragma unroll
        for (int ot = 0; ot < 8; ++ot)
#pragma unroll
            for (int ks = 0; ks < 4; ++ks)
                b[ot][ks] = wp[(ot * 4 + ks) * 64 + lane];
    }

    for (int g = wr; g < groups_per_rel; g += waves_per_rel) {
        int ebase = r * E + g * 16;
        int   colv = ecol[ebase + l15];
        int   rowv = erow[ebase + l15];
        float valv = eval[ebase + l15];

        short8 a[4];
        const unsigned short* hp = Hbf + (size_t)colv * DIM + quad * 8;
#pragma unroll
        for (int ks = 0; ks < 4; ++ks)
            a[ks] = *reinterpret_cast<const short8*>(hp + ks * 32);

        floatx4 acc[8];
#pragma unroll
        for (int ot = 0; ot < 8; ++ot) acc[ot] = (floatx4){0.f, 0.f, 0.f, 0.f};
#pragma unroll
        for (int ot = 0; ot < 8; ++ot)
#pragma unroll
            for (int ks = 0; ks < 4; ++ks)
                acc[ot] = __builtin_amdgcn_mfma_f32_16x16x32_bf16(
                    a[ks], b[ot][ks], acc[ot], 0, 0, 0);

        int   row4[4];
        float val4[4];
#pragma unroll
        for (int reg = 0; reg < 4; ++reg) {
            int src  = quad * 4 + reg;
            row4[reg] = __shfl(rowv, src, 64);
            val4[reg] = __shfl(valv, src, 64);
        }
#pragma unroll
        for (int ot = 0; ot < 8; ++ot)
#pragma unroll
            for (int reg = 0; reg < 4; ++reg) {
                float m = acc[ot][reg] * val4[reg];
                atomicAdd(out + (size_t)row4[reg] * DIM + ot * 16 + l15, m);
            }
    }
}

extern "C" void kernel_launch(void* const* d_in, const int* in_sizes, int n_in,
                              void* d_out, int out_size, void* d_ws, size_t ws_size,
                              hipStream_t stream)
{
    const float* H    = (const float*)d_in[0];
    const float* A    = (const float*)d_in[1];
    const float* V    = (const float*)d_in[2];
    const int*   erow = (const int*)d_in[3];
    const int*   ecol = (const int*)d_in[4];
    const float* eval = (const float*)d_in[5];
    float* out = (float*)d_out;

    int Ne    = in_sizes[0] / DIM;   // 100000
    int NEtot = in_sizes[3];         // 1.6M
    int E     = NEtot / NR;          // 200000

    auto al = [](size_t x) { return (x + 255) & ~(size_t)255; };

    int nbuc = (Ne + BROWS - 1) / BROWS;   // 196

    size_t offHbf    = 0;
    size_t offVfrag  = offHbf    + al((size_t)Ne * DIM * 2);
    size_t offWfrag  = offVfrag  + al((size_t)8192 * 16);
    size_t offAgg    = offWfrag  + al((size_t)16384 * 16);  // sorted1 aliases here
    size_t offRow    = offAgg    + al((size_t)Ne * 512 * 2);
    size_t offBcnt   = offRow    + al(((size_t)Ne + 2) * 4);
    size_t offBstart = offBcnt   + al((size_t)256 * 4);
    size_t offSort   = offBstart + al((size_t)256 * 4);
    size_t total     = offSort   + al((size_t)NEtot * 8);

    char* ws = (char*)d_ws;
    unsigned short* Hbf    = (unsigned short*)(ws + offHbf);
    unsigned short* VfragG = (unsigned short*)(ws + offVfrag);
    unsigned short* Wfrag  = (unsigned short*)(ws + offWfrag);

    int n8 = Ne * DIM / 8;
    h_to_bf<<<(n8 + 255) / 256, 256, 0, stream>>>(H, Hbf, n8);

    if (ws_size < total) {
        // fallback: atomic-scatter path (round 2)
        build_wfrag<<<64, 256, 0, stream>>>(A, V, Wfrag);
        hipMemsetAsync(d_out, 0, (size_t)Ne * DIM * sizeof(float), stream);
        int blocks = 4096;
        int waves_per_rel = blocks * 4 / NR;
        int groups_per_rel = E / 16;
        rgcn_main<<<blocks, 256, 0, stream>>>(Hbf, Wfrag, erow, ecol, eval, out,
                                              E, groups_per_rel, waves_per_rel);
        return;
    }

    unsigned short* Agg      = (unsigned short*)(ws + offAgg);
    int2*           sorted1  = (int2*)(ws + offAgg);   // alias (dead before Agg)
    int*            rowStart = (int*)(ws + offRow);
    int*            bcnt     = (int*)(ws + offBcnt);
    int*            bstart   = (int*)(ws + offBstart);
    int2*           sorted   = (int2*)(ws + offSort);

    build_vfrag<<<32, 256, 0, stream>>>(V, VfragG);

    // two-level bucket sort (no global histogram / scan prologue)
    hipMemsetAsync(bcnt, 0, 256 * 4, stream);
    int sblocks = 512;
    int chunk   = (NEtot + sblocks - 1) / sblocks;   // 3125
    bucket_scatter<<<sblocks, 256, 0, stream>>>(erow, ecol, eval, bcnt,
                                                sorted1, NEtot, E, chunk);
    bucket_scan<<<1, 256, 0, stream>>>(bcnt, bstart, rowStart, nbuc, Ne);
    bucket_sort<<<nbuc, 256, 0, stream>>>(sorted1, bcnt, bstart, rowStart,
                                          sorted, Ne);

    // K_A: 4-basis aggregation (scalarized control path, no atomics)
    agg_kernel<<<(Ne + 3) / 4, 256, 0, stream>>>(Hbf, rowStart, sorted, A,
                                                 Agg, Ne);

    // K_B: out = Agg @ V via MFMA, V-frags in LDS (two 64-col halves,
    // XCD-paired so both halves of a tile set share one L2)
    int nTiles = (Ne + 15) / 16;   // 6250
    vgemm_kernel<<<512, 512, 0, stream>>>(Agg, VfragG, out, Ne, nTiles);
}

// Round 5
// 327.858 us; speedup vs baseline: 1.0937x; 1.0937x over previous
//
#include <hip/hip_runtime.h>

typedef __attribute__((ext_vector_type(8))) short short8;
typedef __attribute__((ext_vector_type(4))) float floatx4;

constexpr int DIM   = 128;   // dim_in == dim_out
constexpr int NB    = 4;     // bases
constexpr int NR    = 8;     // relations
constexpr int BROWS = 512;   // rows per sort bucket
constexpr int BCAP  = 16384; // fixed bucket capacity (mean 8192, +90 sigma)

static __device__ __forceinline__ unsigned short f2bf(float f) {
    unsigned int u = __float_as_uint(f);
    u += 0x7FFFu + ((u >> 16) & 1u);
    return (unsigned short)(u >> 16);
}
static __device__ __forceinline__ float bf_lo(unsigned int h) {
    return __uint_as_float(h << 16);
}
static __device__ __forceinline__ float bf_hi(unsigned int h) {
    return __uint_as_float(h & 0xFFFF0000u);
}

// ---------------------------------------------------------------------------
// Vfrag[b][ot][ks][lane][j] = V[b][k][o], k=ks*32+(lane>>4)*8+j, o=ot*16+(lane&15)
// ---------------------------------------------------------------------------
__global__ __launch_bounds__(256) void build_vfrag(
    const float* __restrict__ V, unsigned short* __restrict__ VfragG)
{
    int idx  = blockIdx.x * 256 + threadIdx.x;   // 0 .. 8191
    int lane = idx & 63;
    int ks   = (idx >> 6) & 3;
    int ot   = (idx >> 8) & 7;
    int b    = idx >> 11;

    int o  = ot * 16 + (lane & 15);
    int kb = ks * 32 + (lane >> 4) * 8;

    short8 v;
#pragma unroll
    for (int j = 0; j < 8; ++j)
        v[j] = (short)f2bf(V[((size_t)b * DIM + kb + j) * DIM + o]);
    *reinterpret_cast<short8*>(VfragG + (size_t)idx * 8) = v;
}

// ---------------------------------------------------------------------------
// W_r fragments (fallback path only)
// ---------------------------------------------------------------------------
__global__ __launch_bounds__(256) void build_wfrag(
    const float* __restrict__ A, const float* __restrict__ V,
    unsigned short* __restrict__ Wfrag)
{
    int idx  = blockIdx.x * 256 + threadIdx.x;   // 0 .. 16383
    int lane = idx & 63;
    int ks   = (idx >> 6) & 3;
    int ot   = (idx >> 8) & 7;
    int r    = idx >> 11;

    int o     = ot * 16 + (lane & 15);
    int kbase = ks * 32 + (lane >> 4) * 8;

    float a0 = A[r * NB + 0], a1 = A[r * NB + 1];
    float a2 = A[r * NB + 2], a3 = A[r * NB + 3];

    short8 v;
#pragma unroll
    for (int j = 0; j < 8; ++j) {
        int k = kbase + j;
        float w = a0 * V[(0 * DIM + k) * DIM + o]
                + a1 * V[(1 * DIM + k) * DIM + o]
                + a2 * V[(2 * DIM + k) * DIM + o]
                + a3 * V[(3 * DIM + k) * DIM + o];
        v[j] = (short)f2bf(w);
    }
    *reinterpret_cast<short8*>(Wfrag + (size_t)idx * 8) = v;
}

// ---------------------------------------------------------------------------
// H (fp32) -> Hbf (bf16), row-major [Ne][128]
// ---------------------------------------------------------------------------
__global__ __launch_bounds__(256) void h_to_bf(
    const float* __restrict__ H, unsigned short* __restrict__ Hbf, int n8)
{
    int i = blockIdx.x * 256 + threadIdx.x;
    if (i >= n8) return;
    const float4* hp = reinterpret_cast<const float4*>(H) + (size_t)i * 2;
    float4 f0 = hp[0];
    float4 f1 = hp[1];
    short8 v;
    v[0] = (short)f2bf(f0.x); v[1] = (short)f2bf(f0.y);
    v[2] = (short)f2bf(f0.z); v[3] = (short)f2bf(f0.w);
    v[4] = (short)f2bf(f1.x); v[5] = (short)f2bf(f1.y);
    v[6] = (short)f2bf(f1.z); v[7] = (short)f2bf(f1.w);
    *reinterpret_cast<short8*>(Hbf + (size_t)i * 8) = v;
}

// ---------------------------------------------------------------------------
// Sort pass 1: scatter edges into fixed-capacity coarse buckets
// ---------------------------------------------------------------------------
__global__ __launch_bounds__(256) void bucket_scatter(
    const int* __restrict__ erow, const int* __restrict__ ecol,
    const float* __restrict__ eval, int* __restrict__ bcnt,
    int2* __restrict__ sorted1, int n, int E, int chunk)
{
    __shared__ int cnt[256];
    __shared__ int base[256];
    int t = threadIdx.x;
    cnt[t] = 0;
    __syncthreads();

    int s = blockIdx.x * chunk;
    int e = s + chunk; if (e > n) e = n;

    for (int i = s + t; i < e; i += 256)
        atomicAdd(&cnt[erow[i] >> 9], 1);
    __syncthreads();

    int c = cnt[t];
    base[t] = (c > 0) ? atomicAdd(&bcnt[t], c) : 0;
    cnt[t] = 0;
    __syncthreads();

    for (int i = s + t; i < e; i += 256) {
        int row = erow[i];
        int bkt = row >> 9;
        int rank = atomicAdd(&cnt[bkt], 1);
        int r = (int)((unsigned)i / (unsigned)E);
        int2 m;
        m.x = ((row & (BROWS - 1)) << 20) | (r << 17) | ecol[i];
        m.y = __float_as_int(eval[i]);
        sorted1[(size_t)bkt * BCAP + base[bkt] + rank] = m;
    }
}

// ---------------------------------------------------------------------------
// Exclusive scan over the 196 bucket counts (single block)
// ---------------------------------------------------------------------------
__global__ __launch_bounds__(256) void bucket_scan(
    const int* __restrict__ bcnt, int* __restrict__ bstart,
    int* __restrict__ rowStart, int nbuc, int Ne)
{
    __shared__ int sd[256];
    int t = threadIdx.x;
    int c = (t < nbuc) ? bcnt[t] : 0;
    sd[t] = c; __syncthreads();
#pragma unroll
    for (int off = 1; off < 256; off <<= 1) {
        int v = (t >= off) ? sd[t - off] : 0;
        __syncthreads();
        sd[t] += v;
        __syncthreads();
    }
    if (t < nbuc) bstart[t] = sd[t] - c;
    if (t == nbuc - 1) rowStart[Ne] = sd[t];
}

// ---------------------------------------------------------------------------
// Sort pass 2: one block per bucket; compacts to exact final positions.
// ---------------------------------------------------------------------------
__global__ __launch_bounds__(256) void bucket_sort(
    const int2* __restrict__ sorted1, const int* __restrict__ bcnt,
    const int* __restrict__ bstart, int* __restrict__ rowStart,
    int2* __restrict__ sorted, int Ne)
{
    __shared__ int hcnt[BROWS];
    __shared__ int hoff[BROWS];
    int b = blockIdx.x;
    int t = threadIdx.x;
    hcnt[t] = 0; hcnt[t + 256] = 0;
    __syncthreads();

    int n = bcnt[b];
    const int2* src = sorted1 + (size_t)b * BCAP;

    for (int i = t; i < n; i += 256)
        atomicAdd(&hcnt[(unsigned)src[i].x >> 20], 1);
    __syncthreads();

    if (t == 0) {
        int run = 0;
#pragma unroll 8
        for (int j = 0; j < BROWS; ++j) { hoff[j] = run; run += hcnt[j]; }
    }
    __syncthreads();

    int bs = bstart[b];
    int rs = b * BROWS;
    int nr = Ne - rs; if (nr > BROWS) nr = BROWS;
    for (int j = t; j < nr; j += 256)
        rowStart[rs + j] = bs + hoff[j];

    hcnt[t] = 0; hcnt[t + 256] = 0;
    __syncthreads();

    for (int i = t; i < n; i += 256) {
        int2 m = src[i];
        int lr = (unsigned)m.x >> 20;
        int pos = bs + hoff[lr] + atomicAdd(&hcnt[lr], 1);
        sorted[pos] = m;
    }
}

// ---------------------------------------------------------------------------
// K_A: basis aggregation. One wave per destination row.
// Output layout is TILE-MAJOR (AggT): for node = t*16 + r, basis b,
// cols c = ks*32 + q*8 + j live at byte
//   t*16384 + b*4096 + ks*1024 + r*64 + q*16 + j*2
// so vgemm's per-(b,ks) wave load is ONE contiguous 1 KB block (single
// coalesced segment) instead of a 16-segment gather. agg's store becomes
// 4x64B segments per instruction (was 1x256B) - small cost on a
// gather-read-dominated kernel. Content per lane is byte-identical.
// ---------------------------------------------------------------------------
__global__ __launch_bounds__(256) void agg_kernel(
    const unsigned short* __restrict__ Hbf,
    const int*  __restrict__ rowStart,
    const int2* __restrict__ sorted,
    const float* __restrict__ Aw,
    unsigned short* __restrict__ AggT, int Ne)
{
    int tid  = threadIdx.x;
    int wid  = __builtin_amdgcn_readfirstlane(blockIdx.x * 4 + (tid >> 6));
    if (wid >= Ne) return;
    int lane = tid & 63;

    int s = __builtin_amdgcn_readfirstlane(rowStart[wid]);
    int e = __builtin_amdgcn_readfirstlane(rowStart[wid + 1]);

    const float4* Af = reinterpret_cast<const float4*>(Aw);

    float2 acc[4];
#pragma unroll
    for (int b = 0; b < 4; ++b) { acc[b].x = 0.f; acc[b].y = 0.f; }

    int i = s;
    for (; i + 8 <= e; i += 8) {
        int kk[8];
        float vv[8];
        unsigned int hh[8];
#pragma unroll
        for (int u = 0; u < 8; ++u) {
            int2 m = sorted[i + u];
            kk[u] = __builtin_amdgcn_readfirstlane(m.x);
            vv[u] = __uint_as_float(__builtin_amdgcn_readfirstlane(m.y));
        }
#pragma unroll
        for (int u = 0; u < 8; ++u)
            hh[u] = reinterpret_cast<const unsigned int*>(
                Hbf + (size_t)(kk[u] & 0x1FFFF) * DIM)[lane];
#pragma unroll
        for (int u = 0; u < 8; ++u) {
            float4 a = Af[((unsigned)kk[u] >> 17) & 7];
            float hx = bf_lo(hh[u]), hy = bf_hi(hh[u]);
            float s0 = vv[u] * a.x, s1 = vv[u] * a.y;
            float s2 = vv[u] * a.z, s3 = vv[u] * a.w;
            acc[0].x += s0 * hx; acc[0].y += s0 * hy;
            acc[1].x += s1 * hx; acc[1].y += s1 * hy;
            acc[2].x += s2 * hx; acc[2].y += s2 * hy;
            acc[3].x += s3 * hx; acc[3].y += s3 * hy;
        }
    }
    for (; i < e; ++i) {
        int2 m = sorted[i];
        int k = __builtin_amdgcn_readfirstlane(m.x);
        float v = __uint_as_float(__builtin_amdgcn_readfirstlane(m.y));
        unsigned int h = reinterpret_cast<const unsigned int*>(
            Hbf + (size_t)(k & 0x1FFFF) * DIM)[lane];
        float4 a = Af[((unsigned)k >> 17) & 7];
        float hx = bf_lo(h), hy = bf_hi(h);
        float s0 = v * a.x, s1 = v * a.y, s2 = v * a.z, s3 = v * a.w;
        acc[0].x += s0 * hx; acc[0].y += s0 * hy;
        acc[1].x += s1 * hx; acc[1].y += s1 * hy;
        acc[2].x += s2 * hx; acc[2].y += s2 * hy;
        acc[3].x += s3 * hx; acc[3].y += s3 * hy;
    }

    // tile-major scatter: cols {2*lane, 2*lane+1} of basis b
    int t = wid >> 4, r = wid & 15;
    size_t base = (size_t)t * 8192 + (size_t)r * 32
                + (size_t)(lane >> 4) * 512
                + (size_t)((lane >> 2) & 3) * 8
                + (size_t)(lane & 3) * 2;          // ushort units
    unsigned short* arow = AggT + base;
#pragma unroll
    for (int b = 0; b < 4; ++b) {
        unsigned int pk = (unsigned int)f2bf(acc[b].x)
                        | ((unsigned int)f2bf(acc[b].y) << 16);
        *reinterpret_cast<unsigned int*>(arow + b * 2048) = pk;
    }
}

// ---------------------------------------------------------------------------
// K_B: out = AggT @ V  (M=Ne, K=512, N=128), MFMA.
// Round-3 proven structure (512 thr, 64 KB LDS, VGPR 128, XCD-paired
// halves). With the tile-major AggT layout each bf[b*4+ks] load covers one
// contiguous aligned 1 KB block per wave -> single-segment coalesced
// dwordx4 (was a 16-segment gather; transaction-rate-bound at 2.6 TB/s).
// ---------------------------------------------------------------------------
__global__ __launch_bounds__(512) void vgemm_kernel(
    const unsigned short* __restrict__ AggT,
    const unsigned short* __restrict__ VfragG,
    float* __restrict__ out, int Ne, int nTiles)
{
    __shared__ short8 ldsV[4096];   // [b][otl][ks][lane], 64 KB
    int half = (blockIdx.x >> 3) & 1;                       // XCD-paired
    int blk  = ((blockIdx.x >> 4) << 3) | (blockIdx.x & 7); // same %8 pair
    int nblk = gridDim.x >> 1;
    int tid  = threadIdx.x;

    for (int i = tid; i < 4096; i += 512) {
        int lane = i & 63, ks = (i >> 6) & 3, otl = (i >> 8) & 3, b = i >> 10;
        int gi = ((b * 8 + half * 4 + otl) * 4 + ks) * 64 + lane;
        ldsV[i] = reinterpret_cast<const short8*>(VfragG)[gi];
    }
    __syncthreads();

    int wave = tid >> 6;
    int lane = tid & 63;
    int quad = lane >> 4, l15 = lane & 15;

    int wgid = blk * 8 + wave;
    int nw   = nblk * 8;

    const short8* AggV = reinterpret_cast<const short8*>(AggT);

    for (int tile = wgid; tile < nTiles; tile += nw) {
        int node = tile * 16 + l15;

        // tile-major: frag (b,ks) for this lane at 16B unit
        //   tile*1024 + b*256 + ks*64 + l15*4 + quad
        const short8* bp = AggV + (size_t)tile * 1024 + l15 * 4 + quad;
        short8 bf[16];
#pragma unroll
        for (int b = 0; b < 4; ++b)
#pragma unroll
            for (int ks = 0; ks < 4; ++ks)
                bf[b * 4 + ks] = bp[b * 256 + ks * 64];

        floatx4 acc[4];
#pragma unroll
        for (int o = 0; o < 4; ++o) acc[o] = (floatx4){0.f, 0.f, 0.f, 0.f};

#pragma unroll
        for (int b = 0; b < 4; ++b)
#pragma unroll
            for (int ks = 0; ks < 4; ++ks)
#pragma unroll
                for (int otl = 0; otl < 4; ++otl)
                    acc[otl] = __builtin_amdgcn_mfma_f32_16x16x32_bf16(
                        ldsV[((b * 4 + otl) * 4 + ks) * 64 + lane],
                        bf[b * 4 + ks], acc[otl], 0, 0, 0);

        if (node < Ne) {
            float* orow = out + (size_t)node * DIM + half * 64;
#pragma unroll
            for (int otl = 0; otl < 4; ++otl) {
                float4 st;
                st.x = acc[otl][0]; st.y = acc[otl][1];
                st.z = acc[otl][2]; st.w = acc[otl][3];
                *reinterpret_cast<float4*>(orow + otl * 16 + quad * 4) = st;
            }
        }
    }
}

// ---------------------------------------------------------------------------
// Fallback (ws too small): round-2 atomic kernel
// ---------------------------------------------------------------------------
__global__ __launch_bounds__(256) void rgcn_main(
    const unsigned short* __restrict__ Hbf,
    const unsigned short* __restrict__ Wfrag,
    const int*   __restrict__ erow,
    const int*   __restrict__ ecol,
    const float* __restrict__ eval,
    float*       __restrict__ out,
    int E, int groups_per_rel, int waves_per_rel)
{
    int wid  = blockIdx.x * 4 + (threadIdx.x >> 6);
    int lane = threadIdx.x & 63;
    int r    = wid & 7;
    int wr   = wid >> 3;
    int quad = lane >> 4;
    int l15  = lane & 15;

    short8 b[8][4];
    {
        const short8* wp = reinterpret_cast<const short8*>(
            Wfrag + (size_t)r * 16384);
#pragma unroll
        for (int ot = 0; ot < 8; ++ot)
#pragma unroll
            for (int ks = 0; ks < 4; ++ks)
                b[ot][ks] = wp[(ot * 4 + ks) * 64 + lane];
    }

    for (int g = wr; g < groups_per_rel; g += waves_per_rel) {
        int ebase = r * E + g * 16;
        int   colv = ecol[ebase + l15];
        int   rowv = erow[ebase + l15];
        float valv = eval[ebase + l15];

        short8 a[4];
        const unsigned short* hp = Hbf + (size_t)colv * DIM + quad * 8;
#pragma unroll
        for (int ks = 0; ks < 4; ++ks)
            a[ks] = *reinterpret_cast<const short8*>(hp + ks * 32);

        floatx4 acc[8];
#pragma unroll
        for (int ot = 0; ot < 8; ++ot) acc[ot] = (floatx4){0.f, 0.f, 0.f, 0.f};
#pragma unroll
        for (int ot = 0; ot < 8; ++ot)
#pragma unroll
            for (int ks = 0; ks < 4; ++ks)
                acc[ot] = __builtin_amdgcn_mfma_f32_16x16x32_bf16(
                    a[ks], b[ot][ks], acc[ot], 0, 0, 0);

        int   row4[4];
        float val4[4];
#pragma unroll
        for (int reg = 0; reg < 4; ++reg) {
            int src  = quad * 4 + reg;
            row4[reg] = __shfl(rowv, src, 64);
            val4[reg] = __shfl(valv, src, 64);
        }
#pragma unroll
        for (int ot = 0; ot < 8; ++ot)
#pragma unroll
            for (int reg = 0; reg < 4; ++reg) {
                float m = acc[ot][reg] * val4[reg];
                atomicAdd(out + (size_t)row4[reg] * DIM + ot * 16 + l15, m);
            }
    }
}

extern "C" void kernel_launch(void* const* d_in, const int* in_sizes, int n_in,
                              void* d_out, int out_size, void* d_ws, size_t ws_size,
                              hipStream_t stream)
{
    const float* H    = (const float*)d_in[0];
    const float* A    = (const float*)d_in[1];
    const float* V    = (const float*)d_in[2];
    const int*   erow = (const int*)d_in[3];
    const int*   ecol = (const int*)d_in[4];
    const float* eval = (const float*)d_in[5];
    float* out = (float*)d_out;

    int Ne    = in_sizes[0] / DIM;   // 100000
    int NEtot = in_sizes[3];         // 1.6M
    int E     = NEtot / NR;          // 200000

    auto al = [](size_t x) { return (x + 255) & ~(size_t)255; };

    int nbuc = (Ne + BROWS - 1) / BROWS;   // 196
    int nTiles = (Ne + 15) / 16;           // 6250 (Ne divisible by 16)

    size_t offHbf    = 0;
    size_t offVfrag  = offHbf    + al((size_t)Ne * DIM * 2);
    size_t offWfrag  = offVfrag  + al((size_t)8192 * 16);
    size_t offAgg    = offWfrag  + al((size_t)16384 * 16);  // sorted1 aliases here
    size_t offRow    = offAgg    + al((size_t)nTiles * 16384);
    size_t offBcnt   = offRow    + al(((size_t)Ne + 2) * 4);
    size_t offBstart = offBcnt   + al((size_t)256 * 4);
    size_t offSort   = offBstart + al((size_t)256 * 4);
    size_t total     = offSort   + al((size_t)NEtot * 8);

    char* ws = (char*)d_ws;
    unsigned short* Hbf    = (unsigned short*)(ws + offHbf);
    unsigned short* VfragG = (unsigned short*)(ws + offVfrag);
    unsigned short* Wfrag  = (unsigned short*)(ws + offWfrag);

    int n8 = Ne * DIM / 8;
    h_to_bf<<<(n8 + 255) / 256, 256, 0, stream>>>(H, Hbf, n8);

    if (ws_size < total) {
        // fallback: atomic-scatter path (round 2)
        build_wfrag<<<64, 256, 0, stream>>>(A, V, Wfrag);
        hipMemsetAsync(d_out, 0, (size_t)Ne * DIM * sizeof(float), stream);
        int blocks = 4096;
        int waves_per_rel = blocks * 4 / NR;
        int groups_per_rel = E / 16;
        rgcn_main<<<blocks, 256, 0, stream>>>(Hbf, Wfrag, erow, ecol, eval, out,
                                              E, groups_per_rel, waves_per_rel);
        return;
    }

    unsigned short* AggT     = (unsigned short*)(ws + offAgg);
    int2*           sorted1  = (int2*)(ws + offAgg);   // alias (dead before AggT)
    int*            rowStart = (int*)(ws + offRow);
    int*            bcnt     = (int*)(ws + offBcnt);
    int*            bstart   = (int*)(ws + offBstart);
    int2*           sorted   = (int2*)(ws + offSort);

    build_vfrag<<<32, 256, 0, stream>>>(V, VfragG);

    // two-level bucket sort (no global histogram / scan prologue)
    hipMemsetAsync(bcnt, 0, 256 * 4, stream);
    int sblocks = 512;
    int chunk   = (NEtot + sblocks - 1) / sblocks;   // 3125
    bucket_scatter<<<sblocks, 256, 0, stream>>>(erow, ecol, eval, bcnt,
                                                sorted1, NEtot, E, chunk);
    bucket_scan<<<1, 256, 0, stream>>>(bcnt, bstart, rowStart, nbuc, Ne);
    bucket_sort<<<nbuc, 256, 0, stream>>>(sorted1, bcnt, bstart, rowStart,
                                          sorted, Ne);

    // K_A: 4-basis aggregation, tile-major output layout
    agg_kernel<<<(Ne + 3) / 4, 256, 0, stream>>>(Hbf, rowStart, sorted, A,
                                                 AggT, Ne);

    // K_B: out = AggT @ V via MFMA, V-frags in LDS (two 64-col halves,
    // XCD-paired so both halves of a tile set share one L2)
    vgemm_kernel<<<512, 512, 0, stream>>>(AggT, VfragG, out, Ne, nTiles);
}

// Round 6
// 324.646 us; speedup vs baseline: 1.1045x; 1.0099x over previous
//
#include <hip/hip_runtime.h>

typedef __attribute__((ext_vector_type(8))) short short8;
typedef __attribute__((ext_vector_type(4))) float floatx4;
typedef __attribute__((ext_vector_type(2))) float floatx2;

constexpr int DIM   = 128;   // dim_in == dim_out
constexpr int NB    = 4;     // bases
constexpr int NR    = 8;     // relations
constexpr int BROWS = 512;   // rows per sort bucket
constexpr int BCAP  = 16384; // fixed bucket capacity (mean 8192, +90 sigma)

static __device__ __forceinline__ unsigned short f2bf(float f) {
    unsigned int u = __float_as_uint(f);
    u += 0x7FFFu + ((u >> 16) & 1u);
    return (unsigned short)(u >> 16);
}
static __device__ __forceinline__ float bf_lo(unsigned int h) {
    return __uint_as_float(h << 16);
}
static __device__ __forceinline__ float bf_hi(unsigned int h) {
    return __uint_as_float(h & 0xFFFF0000u);
}

// ---------------------------------------------------------------------------
// Vfrag[b][ot][ks][lane][j] = V[b][k][o], k=ks*32+(lane>>4)*8+j, o=ot*16+(lane&15)
// ---------------------------------------------------------------------------
__global__ __launch_bounds__(256) void build_vfrag(
    const float* __restrict__ V, unsigned short* __restrict__ VfragG)
{
    int idx  = blockIdx.x * 256 + threadIdx.x;   // 0 .. 8191
    int lane = idx & 63;
    int ks   = (idx >> 6) & 3;
    int ot   = (idx >> 8) & 7;
    int b    = idx >> 11;

    int o  = ot * 16 + (lane & 15);
    int kb = ks * 32 + (lane >> 4) * 8;

    short8 v;
#pragma unroll
    for (int j = 0; j < 8; ++j)
        v[j] = (short)f2bf(V[((size_t)b * DIM + kb + j) * DIM + o]);
    *reinterpret_cast<short8*>(VfragG + (size_t)idx * 8) = v;
}

// ---------------------------------------------------------------------------
// W_r fragments (fallback path only)
// ---------------------------------------------------------------------------
__global__ __launch_bounds__(256) void build_wfrag(
    const float* __restrict__ A, const float* __restrict__ V,
    unsigned short* __restrict__ Wfrag)
{
    int idx  = blockIdx.x * 256 + threadIdx.x;   // 0 .. 16383
    int lane = idx & 63;
    int ks   = (idx >> 6) & 3;
    int ot   = (idx >> 8) & 7;
    int r    = idx >> 11;

    int o     = ot * 16 + (lane & 15);
    int kbase = ks * 32 + (lane >> 4) * 8;

    float a0 = A[r * NB + 0], a1 = A[r * NB + 1];
    float a2 = A[r * NB + 2], a3 = A[r * NB + 3];

    short8 v;
#pragma unroll
    for (int j = 0; j < 8; ++j) {
        int k = kbase + j;
        float w = a0 * V[(0 * DIM + k) * DIM + o]
                + a1 * V[(1 * DIM + k) * DIM + o]
                + a2 * V[(2 * DIM + k) * DIM + o]
                + a3 * V[(3 * DIM + k) * DIM + o];
        v[j] = (short)f2bf(w);
    }
    *reinterpret_cast<short8*>(Wfrag + (size_t)idx * 8) = v;
}

// ---------------------------------------------------------------------------
// H (fp32) -> Hbf (bf16), row-major [Ne][128]
// ---------------------------------------------------------------------------
__global__ __launch_bounds__(256) void h_to_bf(
    const float* __restrict__ H, unsigned short* __restrict__ Hbf, int n8)
{
    int i = blockIdx.x * 256 + threadIdx.x;
    if (i >= n8) return;
    const float4* hp = reinterpret_cast<const float4*>(H) + (size_t)i * 2;
    float4 f0 = hp[0];
    float4 f1 = hp[1];
    short8 v;
    v[0] = (short)f2bf(f0.x); v[1] = (short)f2bf(f0.y);
    v[2] = (short)f2bf(f0.z); v[3] = (short)f2bf(f0.w);
    v[4] = (short)f2bf(f1.x); v[5] = (short)f2bf(f1.y);
    v[6] = (short)f2bf(f1.z); v[7] = (short)f2bf(f1.w);
    *reinterpret_cast<short8*>(Hbf + (size_t)i * 8) = v;
}

// ---------------------------------------------------------------------------
// Sort pass 1: scatter edges into fixed-capacity coarse buckets
// ---------------------------------------------------------------------------
__global__ __launch_bounds__(256) void bucket_scatter(
    const int* __restrict__ erow, const int* __restrict__ ecol,
    const float* __restrict__ eval, int* __restrict__ bcnt,
    int2* __restrict__ sorted1, int n, int E, int chunk)
{
    __shared__ int cnt[256];
    __shared__ int base[256];
    int t = threadIdx.x;
    cnt[t] = 0;
    __syncthreads();

    int s = blockIdx.x * chunk;
    int e = s + chunk; if (e > n) e = n;

    for (int i = s + t; i < e; i += 256)
        atomicAdd(&cnt[erow[i] >> 9], 1);
    __syncthreads();

    int c = cnt[t];
    base[t] = (c > 0) ? atomicAdd(&bcnt[t], c) : 0;
    cnt[t] = 0;
    __syncthreads();

    for (int i = s + t; i < e; i += 256) {
        int row = erow[i];
        int bkt = row >> 9;
        int rank = atomicAdd(&cnt[bkt], 1);
        int r = (int)((unsigned)i / (unsigned)E);
        int2 m;
        m.x = ((row & (BROWS - 1)) << 20) | (r << 17) | ecol[i];
        m.y = __float_as_int(eval[i]);
        sorted1[(size_t)bkt * BCAP + base[bkt] + rank] = m;
    }
}

// ---------------------------------------------------------------------------
// Sort pass 2: one block per bucket; compacts to exact final positions.
// The 196-entry bucket-count prefix scan is folded in (every block scans
// redundantly in LDS, ~1 us) -> the separate bucket_scan launch is gone.
// ---------------------------------------------------------------------------
__global__ __launch_bounds__(256) void bucket_sort(
    const int2* __restrict__ sorted1, const int* __restrict__ bcnt,
    int* __restrict__ rowStart, int2* __restrict__ sorted, int Ne, int nbuc)
{
    __shared__ int hcnt[BROWS];
    __shared__ int hoff[BROWS];
    __shared__ int sd[256];
    int b = blockIdx.x;
    int t = threadIdx.x;
    hcnt[t] = 0; hcnt[t + 256] = 0;
    int c = (t < nbuc) ? bcnt[t] : 0;
    sd[t] = c;
    __syncthreads();
#pragma unroll
    for (int off = 1; off < 256; off <<= 1) {
        int v = (t >= off) ? sd[t - off] : 0;
        __syncthreads();
        sd[t] += v;
        __syncthreads();
    }
    if (b == 0 && t == nbuc - 1) rowStart[Ne] = sd[t];

    int n  = bcnt[b];
    int bs = sd[b] - n;               // exclusive prefix (LDS broadcast)
    const int2* src = sorted1 + (size_t)b * BCAP;

    for (int i = t; i < n; i += 256)
        atomicAdd(&hcnt[(unsigned)src[i].x >> 20], 1);
    __syncthreads();

    if (t == 0) {
        int run = 0;
#pragma unroll 8
        for (int j = 0; j < BROWS; ++j) { hoff[j] = run; run += hcnt[j]; }
    }
    __syncthreads();

    int rs = b * BROWS;
    int nr = Ne - rs; if (nr > BROWS) nr = BROWS;
    for (int j = t; j < nr; j += 256)
        rowStart[rs + j] = bs + hoff[j];

    hcnt[t] = 0; hcnt[t + 256] = 0;
    __syncthreads();

    for (int i = t; i < n; i += 256) {
        int2 m = src[i];
        int lr = (unsigned)m.x >> 20;
        int pos = bs + hoff[lr] + atomicAdd(&hcnt[lr], 1);
        sorted[pos] = m;
    }
}

// ---------------------------------------------------------------------------
// K_A: basis aggregation. One wave per destination row. Tile-major output
// (see round-5 comment). Two changes vs round-5:
//  * packed f32 accumulation (floatx2 -> v_pk_fma_f32): ~14 -> ~9 VALU/edge
//  * 2-stage software pipeline (named A/B groups, wave-uniform branches):
//    group k+1's 8 gathers are issued BEFORE group k's FMAs, keeping ~8
//    gathers in flight under VALU work (VALUBusy was 52% with both pipes
//    alternating; neither saturated).
// ---------------------------------------------------------------------------
#define AGG_LOAD8(kk, vv, hh, base)                                          \
    _Pragma("unroll")                                                        \
    for (int u = 0; u < 8; ++u) {                                            \
        int2 m = sorted[(base) + u];                                         \
        kk[u] = __builtin_amdgcn_readfirstlane(m.x);                         \
        vv[u] = __uint_as_float(__builtin_amdgcn_readfirstlane(m.y));        \
    }                                                                        \
    _Pragma("unroll")                                                        \
    for (int u = 0; u < 8; ++u)                                              \
        hh[u] = reinterpret_cast<const unsigned int*>(                       \
            Hbf + (size_t)(kk[u] & 0x1FFFF) * DIM)[lane];

#define AGG_FMA8(kk, vv, hh)                                                 \
    _Pragma("unroll")                                                        \
    for (int u = 0; u < 8; ++u) {                                            \
        float4 a = Af[((unsigned)kk[u] >> 17) & 7];                          \
        floatx2 h; h[0] = bf_lo(hh[u]); h[1] = bf_hi(hh[u]);                 \
        float s0 = vv[u] * a.x, s1 = vv[u] * a.y;                            \
        float s2 = vv[u] * a.z, s3 = vv[u] * a.w;                            \
        acc[0] += (floatx2){s0, s0} * h;                                     \
        acc[1] += (floatx2){s1, s1} * h;                                     \
        acc[2] += (floatx2){s2, s2} * h;                                     \
        acc[3] += (floatx2){s3, s3} * h;                                     \
    }

__global__ __launch_bounds__(256) void agg_kernel(
    const unsigned short* __restrict__ Hbf,
    const int*  __restrict__ rowStart,
    const int2* __restrict__ sorted,
    const float* __restrict__ Aw,
    unsigned short* __restrict__ AggT, int Ne)
{
    int tid  = threadIdx.x;
    int wid  = __builtin_amdgcn_readfirstlane(blockIdx.x * 4 + (tid >> 6));
    if (wid >= Ne) return;
    int lane = tid & 63;

    int s = __builtin_amdgcn_readfirstlane(rowStart[wid]);
    int e = __builtin_amdgcn_readfirstlane(rowStart[wid + 1]);

    const float4* Af = reinterpret_cast<const float4*>(Aw);

    floatx2 acc[4];
#pragma unroll
    for (int b = 0; b < 4; ++b) acc[b] = (floatx2){0.f, 0.f};

    int i = s;
    if (i + 8 <= e) {
        int kkA[8], kkB[8];
        float vvA[8], vvB[8];
        unsigned int hhA[8], hhB[8];
        AGG_LOAD8(kkA, vvA, hhA, i); i += 8;
        for (;;) {
            if (i + 8 <= e) {
                AGG_LOAD8(kkB, vvB, hhB, i); i += 8;
                AGG_FMA8(kkA, vvA, hhA);
            } else { AGG_FMA8(kkA, vvA, hhA); break; }
            if (i + 8 <= e) {
                AGG_LOAD8(kkA, vvA, hhA, i); i += 8;
                AGG_FMA8(kkB, vvB, hhB);
            } else { AGG_FMA8(kkB, vvB, hhB); break; }
        }
    }
    for (; i < e; ++i) {
        int2 m = sorted[i];
        int k = __builtin_amdgcn_readfirstlane(m.x);
        float v = __uint_as_float(__builtin_amdgcn_readfirstlane(m.y));
        unsigned int hu = reinterpret_cast<const unsigned int*>(
            Hbf + (size_t)(k & 0x1FFFF) * DIM)[lane];
        float4 a = Af[((unsigned)k >> 17) & 7];
        floatx2 h; h[0] = bf_lo(hu); h[1] = bf_hi(hu);
        float s0 = v * a.x, s1 = v * a.y, s2 = v * a.z, s3 = v * a.w;
        acc[0] += (floatx2){s0, s0} * h;
        acc[1] += (floatx2){s1, s1} * h;
        acc[2] += (floatx2){s2, s2} * h;
        acc[3] += (floatx2){s3, s3} * h;
    }

    // tile-major scatter: cols {2*lane, 2*lane+1} of basis b
    int t = wid >> 4, r = wid & 15;
    size_t base = (size_t)t * 8192 + (size_t)r * 32
                + (size_t)(lane >> 4) * 512
                + (size_t)((lane >> 2) & 3) * 8
                + (size_t)(lane & 3) * 2;          // ushort units
    unsigned short* arow = AggT + base;
#pragma unroll
    for (int b = 0; b < 4; ++b) {
        unsigned int pk = (unsigned int)f2bf(acc[b][0])
                        | ((unsigned int)f2bf(acc[b][1]) << 16);
        *reinterpret_cast<unsigned int*>(arow + b * 2048) = pk;
    }
}

// ---------------------------------------------------------------------------
// K_B: out = AggT @ V  (M=Ne, K=512, N=128), MFMA.
// Round-3 proven structure (512 thr, 64 KB LDS, VGPR 128, XCD-paired
// halves). With the tile-major AggT layout each bf[b*4+ks] load covers one
// contiguous aligned 1 KB block per wave -> single-segment coalesced
// dwordx4 (was a 16-segment gather; transaction-rate-bound at 2.6 TB/s).
// ---------------------------------------------------------------------------
__global__ __launch_bounds__(512) void vgemm_kernel(
    const unsigned short* __restrict__ AggT,
    const unsigned short* __restrict__ VfragG,
    float* __restrict__ out, int Ne, int nTiles)
{
    __shared__ short8 ldsV[4096];   // [b][otl][ks][lane], 64 KB
    int half = (blockIdx.x >> 3) & 1;                       // XCD-paired
    int blk  = ((blockIdx.x >> 4) << 3) | (blockIdx.x & 7); // same %8 pair
    int nblk = gridDim.x >> 1;
    int tid  = threadIdx.x;

    for (int i = tid; i < 4096; i += 512) {
        int lane = i & 63, ks = (i >> 6) & 3, otl = (i >> 8) & 3, b = i >> 10;
        int gi = ((b * 8 + half * 4 + otl) * 4 + ks) * 64 + lane;
        ldsV[i] = reinterpret_cast<const short8*>(VfragG)[gi];
    }
    __syncthreads();

    int wave = tid >> 6;
    int lane = tid & 63;
    int quad = lane >> 4, l15 = lane & 15;

    int wgid = blk * 8 + wave;
    int nw   = nblk * 8;

    const short8* AggV = reinterpret_cast<const short8*>(AggT);

    for (int tile = wgid; tile < nTiles; tile += nw) {
        int node = tile * 16 + l15;

        // tile-major: frag (b,ks) for this lane at 16B unit
        //   tile*1024 + b*256 + ks*64 + l15*4 + quad
        const short8* bp = AggV + (size_t)tile * 1024 + l15 * 4 + quad;
        short8 bf[16];
#pragma unroll
        for (int b = 0; b < 4; ++b)
#pragma unroll
            for (int ks = 0; ks < 4; ++ks)
                bf[b * 4 + ks] = bp[b * 256 + ks * 64];

        floatx4 acc[4];
#pragma unroll
        for (int o = 0; o < 4; ++o) acc[o] = (floatx4){0.f, 0.f, 0.f, 0.f};

#pragma unroll
        for (int b = 0; b < 4; ++b)
#pragma unroll
            for (int ks = 0; ks < 4; ++ks)
#pragma unroll
                for (int otl = 0; otl < 4; ++otl)
                    acc[otl] = __builtin_amdgcn_mfma_f32_16x16x32_bf16(
                        ldsV[((b * 4 + otl) * 4 + ks) * 64 + lane],
                        bf[b * 4 + ks], acc[otl], 0, 0, 0);

        if (node < Ne) {
            float* orow = out + (size_t)node * DIM + half * 64;
#pragma unroll
            for (int otl = 0; otl < 4; ++otl) {
                float4 st;
                st.x = acc[otl][0]; st.y = acc[otl][1];
                st.z = acc[otl][2]; st.w = acc[otl][3];
                *reinterpret_cast<float4*>(orow + otl * 16 + quad * 4) = st;
            }
        }
    }
}

// ---------------------------------------------------------------------------
// Fallback (ws too small): round-2 atomic kernel
// ---------------------------------------------------------------------------
__global__ __launch_bounds__(256) void rgcn_main(
    const unsigned short* __restrict__ Hbf,
    const unsigned short* __restrict__ Wfrag,
    const int*   __restrict__ erow,
    const int*   __restrict__ ecol,
    const float* __restrict__ eval,
    float*       __restrict__ out,
    int E, int groups_per_rel, int waves_per_rel)
{
    int wid  = blockIdx.x * 4 + (threadIdx.x >> 6);
    int lane = threadIdx.x & 63;
    int r    = wid & 7;
    int wr   = wid >> 3;
    int quad = lane >> 4;
    int l15  = lane & 15;

    short8 b[8][4];
    {
        const short8* wp = reinterpret_cast<const short8*>(
            Wfrag + (size_t)r * 16384);
#pragma unroll
        for (int ot = 0; ot < 8; ++ot)
#pragma unroll
            for (int ks = 0; ks < 4; ++ks)
                b[ot][ks] = wp[(ot * 4 + ks) * 64 + lane];
    }

    for (int g = wr; g < groups_per_rel; g += waves_per_rel) {
        int ebase = r * E + g * 16;
        int   colv = ecol[ebase + l15];
        int   rowv = erow[ebase + l15];
        float valv = eval[ebase + l15];

        short8 a[4];
        const unsigned short* hp = Hbf + (size_t)colv * DIM + quad * 8;
#pragma unroll
        for (int ks = 0; ks < 4; ++ks)
            a[ks] = *reinterpret_cast<const short8*>(hp + ks * 32);

        floatx4 acc[8];
#pragma unroll
        for (int ot = 0; ot < 8; ++ot) acc[ot] = (floatx4){0.f, 0.f, 0.f, 0.f};
#pragma unroll
        for (int ot = 0; ot < 8; ++ot)
#pragma unroll
            for (int ks = 0; ks < 4; ++ks)
                acc[ot] = __builtin_amdgcn_mfma_f32_16x16x32_bf16(
                    a[ks], b[ot][ks], acc[ot], 0, 0, 0);

        int   row4[4];
        float val4[4];
#pragma unroll
        for (int reg = 0; reg < 4; ++reg) {
            int src  = quad * 4 + reg;
            row4[reg] = __shfl(rowv, src, 64);
            val4[reg] = __shfl(valv, src, 64);
        }
#pragma unroll
        for (int ot = 0; ot < 8; ++ot)
#pragma unroll
            for (int reg = 0; reg < 4; ++reg) {
                float m = acc[ot][reg] * val4[reg];
                atomicAdd(out + (size_t)row4[reg] * DIM + ot * 16 + l15, m);
            }
    }
}

extern "C" void kernel_launch(void* const* d_in, const int* in_sizes, int n_in,
                              void* d_out, int out_size, void* d_ws, size_t ws_size,
                              hipStream_t stream)
{
    const float* H    = (const float*)d_in[0];
    const float* A    = (const float*)d_in[1];
    const float* V    = (const float*)d_in[2];
    const int*   erow = (const int*)d_in[3];
    const int*   ecol = (const int*)d_in[4];
    const float* eval = (const float*)d_in[5];
    float* out = (float*)d_out;

    int Ne    = in_sizes[0] / DIM;   // 100000
    int NEtot = in_sizes[3];         // 1.6M
    int E     = NEtot / NR;          // 200000

    auto al = [](size_t x) { return (x + 255) & ~(size_t)255; };

    int nbuc = (Ne + BROWS - 1) / BROWS;   // 196
    int nTiles = (Ne + 15) / 16;           // 6250 (Ne divisible by 16)

    size_t offHbf    = 0;
    size_t offVfrag  = offHbf    + al((size_t)Ne * DIM * 2);
    size_t offWfrag  = offVfrag  + al((size_t)8192 * 16);
    size_t offAgg    = offWfrag  + al((size_t)16384 * 16);  // sorted1 aliases here
    size_t offRow    = offAgg    + al((size_t)nTiles * 16384);
    size_t offBcnt   = offRow    + al(((size_t)Ne + 2) * 4);
    size_t offSort   = offBcnt   + al((size_t)256 * 4);
    size_t total     = offSort   + al((size_t)NEtot * 8);

    char* ws = (char*)d_ws;
    unsigned short* Hbf    = (unsigned short*)(ws + offHbf);
    unsigned short* VfragG = (unsigned short*)(ws + offVfrag);
    unsigned short* Wfrag  = (unsigned short*)(ws + offWfrag);

    int n8 = Ne * DIM / 8;
    h_to_bf<<<(n8 + 255) / 256, 256, 0, stream>>>(H, Hbf, n8);

    if (ws_size < total) {
        // fallback: atomic-scatter path (round 2)
        build_wfrag<<<64, 256, 0, stream>>>(A, V, Wfrag);
        hipMemsetAsync(d_out, 0, (size_t)Ne * DIM * sizeof(float), stream);
        int blocks = 4096;
        int waves_per_rel = blocks * 4 / NR;
        int groups_per_rel = E / 16;
        rgcn_main<<<blocks, 256, 0, stream>>>(Hbf, Wfrag, erow, ecol, eval, out,
                                              E, groups_per_rel, waves_per_rel);
        return;
    }

    unsigned short* AggT     = (unsigned short*)(ws + offAgg);
    int2*           sorted1  = (int2*)(ws + offAgg);   // alias (dead before AggT)
    int*            rowStart = (int*)(ws + offRow);
    int*            bcnt     = (int*)(ws + offBcnt);
    int2*           sorted   = (int2*)(ws + offSort);

    build_vfrag<<<32, 256, 0, stream>>>(V, VfragG);

    // two-level bucket sort (scan folded into pass 2)
    hipMemsetAsync(bcnt, 0, 256 * 4, stream);
    int sblocks = 512;
    int chunk   = (NEtot + sblocks - 1) / sblocks;   // 3125
    bucket_scatter<<<sblocks, 256, 0, stream>>>(erow, ecol, eval, bcnt,
                                                sorted1, NEtot, E, chunk);
    bucket_sort<<<nbuc, 256, 0, stream>>>(sorted1, bcnt, rowStart,
                                          sorted, Ne, nbuc);

    // K_A: 4-basis aggregation, tile-major output layout
    agg_kernel<<<(Ne + 3) / 4, 256, 0, stream>>>(Hbf, rowStart, sorted, A,
                                                 AggT, Ne);

    // K_B: out = AggT @ V via MFMA, V-frags in LDS (two 64-col halves,
    // XCD-paired so both halves of a tile set share one L2)
    vgemm_kernel<<<512, 512, 0, stream>>>(AggT, VfragG, out, Ne, nTiles);
}

// Round 8
// 322.446 us; speedup vs baseline: 1.1120x; 1.0068x over previous
//
#include <hip/hip_runtime.h>

typedef __attribute__((ext_vector_type(8))) short short8;
typedef __attribute__((ext_vector_type(4))) float floatx4;
typedef __attribute__((ext_vector_type(2))) float floatx2;

constexpr int DIM   = 128;   // dim_in == dim_out
constexpr int NB    = 4;     // bases
constexpr int NR    = 8;     // relations
constexpr int BROWS = 512;   // rows per sort bucket
constexpr int BCAP  = 16384; // fixed bucket capacity (mean 8192, +90 sigma)

static __device__ __forceinline__ unsigned short f2bf(float f) {
    unsigned int u = __float_as_uint(f);
    u += 0x7FFFu + ((u >> 16) & 1u);
    return (unsigned short)(u >> 16);
}
static __device__ __forceinline__ float bf_lo(unsigned int h) {
    return __uint_as_float(h << 16);
}
static __device__ __forceinline__ float bf_hi(unsigned int h) {
    return __uint_as_float(h & 0xFFFF0000u);
}

// ---------------------------------------------------------------------------
// Vfrag[b][ot][ks][lane][j] = V[b][k][o], k=ks*32+(lane>>4)*8+j, o=ot*16+(lane&15)
// ---------------------------------------------------------------------------
__global__ __launch_bounds__(256) void build_vfrag(
    const float* __restrict__ V, unsigned short* __restrict__ VfragG)
{
    int idx  = blockIdx.x * 256 + threadIdx.x;   // 0 .. 8191
    int lane = idx & 63;
    int ks   = (idx >> 6) & 3;
    int ot   = (idx >> 8) & 7;
    int b    = idx >> 11;

    int o  = ot * 16 + (lane & 15);
    int kb = ks * 32 + (lane >> 4) * 8;

    short8 v;
#pragma unroll
    for (int j = 0; j < 8; ++j)
        v[j] = (short)f2bf(V[((size_t)b * DIM + kb + j) * DIM + o]);
    *reinterpret_cast<short8*>(VfragG + (size_t)idx * 8) = v;
}

// ---------------------------------------------------------------------------
// W_r fragments (fallback path only)
// ---------------------------------------------------------------------------
__global__ __launch_bounds__(256) void build_wfrag(
    const float* __restrict__ A, const float* __restrict__ V,
    unsigned short* __restrict__ Wfrag)
{
    int idx  = blockIdx.x * 256 + threadIdx.x;   // 0 .. 16383
    int lane = idx & 63;
    int ks   = (idx >> 6) & 3;
    int ot   = (idx >> 8) & 7;
    int r    = idx >> 11;

    int o     = ot * 16 + (lane & 15);
    int kbase = ks * 32 + (lane >> 4) * 8;

    float a0 = A[r * NB + 0], a1 = A[r * NB + 1];
    float a2 = A[r * NB + 2], a3 = A[r * NB + 3];

    short8 v;
#pragma unroll
    for (int j = 0; j < 8; ++j) {
        int k = kbase + j;
        float w = a0 * V[(0 * DIM + k) * DIM + o]
                + a1 * V[(1 * DIM + k) * DIM + o]
                + a2 * V[(2 * DIM + k) * DIM + o]
                + a3 * V[(3 * DIM + k) * DIM + o];
        v[j] = (short)f2bf(w);
    }
    *reinterpret_cast<short8*>(Wfrag + (size_t)idx * 8) = v;
}

// ---------------------------------------------------------------------------
// H (fp32) -> Hbf (bf16), row-major [Ne][128]
// ---------------------------------------------------------------------------
__global__ __launch_bounds__(256) void h_to_bf(
    const float* __restrict__ H, unsigned short* __restrict__ Hbf, int n8)
{
    int i = blockIdx.x * 256 + threadIdx.x;
    if (i >= n8) return;
    const float4* hp = reinterpret_cast<const float4*>(H) + (size_t)i * 2;
    float4 f0 = hp[0];
    float4 f1 = hp[1];
    short8 v;
    v[0] = (short)f2bf(f0.x); v[1] = (short)f2bf(f0.y);
    v[2] = (short)f2bf(f0.z); v[3] = (short)f2bf(f0.w);
    v[4] = (short)f2bf(f1.x); v[5] = (short)f2bf(f1.y);
    v[6] = (short)f2bf(f1.z); v[7] = (short)f2bf(f1.w);
    *reinterpret_cast<short8*>(Hbf + (size_t)i * 8) = v;
}

// ---------------------------------------------------------------------------
// Sort pass 1: scatter edges into fixed-capacity coarse buckets.
// 1024 blocks (was 512): 2x waves in flight for the scattered 8-B stores
// (latency-bound phase).
// ---------------------------------------------------------------------------
__global__ __launch_bounds__(256) void bucket_scatter(
    const int* __restrict__ erow, const int* __restrict__ ecol,
    const float* __restrict__ eval, int* __restrict__ bcnt,
    int2* __restrict__ sorted1, int n, int E, int chunk)
{
    __shared__ int cnt[256];
    __shared__ int base[256];
    int t = threadIdx.x;
    cnt[t] = 0;
    __syncthreads();

    int s = blockIdx.x * chunk;
    int e = s + chunk; if (e > n) e = n;

    for (int i = s + t; i < e; i += 256)
        atomicAdd(&cnt[erow[i] >> 9], 1);
    __syncthreads();

    int c = cnt[t];
    base[t] = (c > 0) ? atomicAdd(&bcnt[t], c) : 0;
    cnt[t] = 0;
    __syncthreads();

    for (int i = s + t; i < e; i += 256) {
        int row = erow[i];
        int bkt = row >> 9;
        int rank = atomicAdd(&cnt[bkt], 1);
        int r = (int)((unsigned)i / (unsigned)E);
        int2 m;
        m.x = ((row & (BROWS - 1)) << 20) | (r << 17) | ecol[i];
        m.y = __float_as_int(eval[i]);
        sorted1[(size_t)bkt * BCAP + base[bkt] + rank] = m;
    }
}

// ---------------------------------------------------------------------------
// Sort pass 2: one block per bucket; compacts to exact final positions.
// 1024 threads/block (16 waves, was 256 thr = 3 waves/CU avg) + parallel
// 512-wide Hillis-Steele scan (replaces the serial t==0 scan, ~4 us/block).
// Identical output (stable partition by local row, same rowStart).
// ---------------------------------------------------------------------------
__global__ __launch_bounds__(1024) void bucket_sort(
    const int2* __restrict__ sorted1, const int* __restrict__ bcnt,
    int* __restrict__ rowStart, int2* __restrict__ sorted, int Ne, int nbuc)
{
    __shared__ int hcnt[BROWS];   // per-local-row counts, then rank counters
    __shared__ int hoff[BROWS];   // per-local-row exclusive offsets
    __shared__ int sd[256];       // bucket-count inclusive scan
    int b = blockIdx.x;
    int t = threadIdx.x;

    for (int i = t; i < BROWS; i += 1024) hcnt[i] = 0;

    if (t < 256) sd[t] = (t < nbuc) ? bcnt[t] : 0;
    __syncthreads();
#pragma unroll
    for (int off = 1; off < 256; off <<= 1) {
        int v = (t < 256 && t >= off) ? sd[t - off] : 0;
        __syncthreads();
        if (t < 256) sd[t] += v;
        __syncthreads();
    }
    if (b == 0 && t == nbuc - 1) rowStart[Ne] = sd[t];

    int n  = bcnt[b];
    int bs = sd[b] - n;               // exclusive prefix of this bucket
    const int2* src = sorted1 + (size_t)b * BCAP;

    for (int i = t; i < n; i += 1024)
        atomicAdd(&hcnt[(unsigned)src[i].x >> 20], 1);
    __syncthreads();

    // parallel exclusive scan of the 512 row counts
    if (t < BROWS) hoff[t] = hcnt[t];
    __syncthreads();
#pragma unroll
    for (int off = 1; off < BROWS; off <<= 1) {
        int v = (t < BROWS && t >= off) ? hoff[t - off] : 0;
        __syncthreads();
        if (t < BROWS) hoff[t] += v;
        __syncthreads();
    }
    if (t < BROWS) hoff[t] -= hcnt[t];   // own-element only: no hazard
    __syncthreads();

    int rs = b * BROWS;
    int nr = Ne - rs; if (nr > BROWS) nr = BROWS;
    for (int j = t; j < nr; j += 1024)
        rowStart[rs + j] = bs + hoff[j];

    for (int i = t; i < BROWS; i += 1024) hcnt[i] = 0;
    __syncthreads();

    for (int i = t; i < n; i += 1024) {
        int2 m = src[i];
        int lr = (unsigned)m.x >> 20;
        int pos = bs + hoff[lr] + atomicAdd(&hcnt[lr], 1);
        sorted[pos] = m;
    }
}

// ---------------------------------------------------------------------------
// K_A: basis aggregation. One wave per destination row. Tile-major output.
// Packed f32 accumulation + 2-stage gather pipeline (round-6; at its
// structural gather floor ~73 us — per-XCD L2 (4 MB) cannot hold the
// 25.6 MB H working set under random cols).
// ---------------------------------------------------------------------------
#define AGG_LOAD8(kk, vv, hh, base)                                          \
    _Pragma("unroll")                                                        \
    for (int u = 0; u < 8; ++u) {                                            \
        int2 m = sorted[(base) + u];                                         \
        kk[u] = __builtin_amdgcn_readfirstlane(m.x);                         \
        vv[u] = __uint_as_float(__builtin_amdgcn_readfirstlane(m.y));        \
    }                                                                        \
    _Pragma("unroll")                                                        \
    for (int u = 0; u < 8; ++u)                                              \
        hh[u] = reinterpret_cast<const unsigned int*>(                       \
            Hbf + (size_t)(kk[u] & 0x1FFFF) * DIM)[lane];

#define AGG_FMA8(kk, vv, hh)                                                 \
    _Pragma("unroll")                                                        \
    for (int u = 0; u < 8; ++u) {                                            \
        float4 a = Af[((unsigned)kk[u] >> 17) & 7];                          \
        floatx2 h; h[0] = bf_lo(hh[u]); h[1] = bf_hi(hh[u]);                 \
        float s0 = vv[u] * a.x, s1 = vv[u] * a.y;                            \
        float s2 = vv[u] * a.z, s3 = vv[u] * a.w;                            \
        acc[0] += (floatx2){s0, s0} * h;                                     \
        acc[1] += (floatx2){s1, s1} * h;                                     \
        acc[2] += (floatx2){s2, s2} * h;                                     \
        acc[3] += (floatx2){s3, s3} * h;                                     \
    }

__global__ __launch_bounds__(256) void agg_kernel(
    const unsigned short* __restrict__ Hbf,
    const int*  __restrict__ rowStart,
    const int2* __restrict__ sorted,
    const float* __restrict__ Aw,
    unsigned short* __restrict__ AggT, int Ne)
{
    int tid  = threadIdx.x;
    int wid  = __builtin_amdgcn_readfirstlane(blockIdx.x * 4 + (tid >> 6));
    if (wid >= Ne) return;
    int lane = tid & 63;

    int s = __builtin_amdgcn_readfirstlane(rowStart[wid]);
    int e = __builtin_amdgcn_readfirstlane(rowStart[wid + 1]);

    const float4* Af = reinterpret_cast<const float4*>(Aw);

    floatx2 acc[4];
#pragma unroll
    for (int b = 0; b < 4; ++b) acc[b] = (floatx2){0.f, 0.f};

    int i = s;
    if (i + 8 <= e) {
        int kkA[8], kkB[8];
        float vvA[8], vvB[8];
        unsigned int hhA[8], hhB[8];
        AGG_LOAD8(kkA, vvA, hhA, i); i += 8;
        for (;;) {
            if (i + 8 <= e) {
                AGG_LOAD8(kkB, vvB, hhB, i); i += 8;
                AGG_FMA8(kkA, vvA, hhA);
            } else { AGG_FMA8(kkA, vvA, hhA); break; }
            if (i + 8 <= e) {
                AGG_LOAD8(kkA, vvA, hhA, i); i += 8;
                AGG_FMA8(kkB, vvB, hhB);
            } else { AGG_FMA8(kkB, vvB, hhB); break; }
        }
    }
    for (; i < e; ++i) {
        int2 m = sorted[i];
        int k = __builtin_amdgcn_readfirstlane(m.x);
        float v = __uint_as_float(__builtin_amdgcn_readfirstlane(m.y));
        unsigned int hu = reinterpret_cast<const unsigned int*>(
            Hbf + (size_t)(k & 0x1FFFF) * DIM)[lane];
        float4 a = Af[((unsigned)k >> 17) & 7];
        floatx2 h; h[0] = bf_lo(hu); h[1] = bf_hi(hu);
        float s0 = v * a.x, s1 = v * a.y, s2 = v * a.z, s3 = v * a.w;
        acc[0] += (floatx2){s0, s0} * h;
        acc[1] += (floatx2){s1, s1} * h;
        acc[2] += (floatx2){s2, s2} * h;
        acc[3] += (floatx2){s3, s3} * h;
    }

    // tile-major scatter: cols {2*lane, 2*lane+1} of basis b
    int t = wid >> 4, r = wid & 15;
    size_t base = (size_t)t * 8192 + (size_t)r * 32
                + (size_t)(lane >> 4) * 512
                + (size_t)((lane >> 2) & 3) * 8
                + (size_t)(lane & 3) * 2;          // ushort units
    unsigned short* arow = AggT + base;
#pragma unroll
    for (int b = 0; b < 4; ++b) {
        unsigned int pk = (unsigned int)f2bf(acc[b][0])
                        | ((unsigned int)f2bf(acc[b][1]) << 16);
        *reinterpret_cast<unsigned int*>(arow + b * 2048) = pk;
    }
}

// ---------------------------------------------------------------------------
// K_B: out = AggT @ V  (M=Ne, K=512, N=128), MFMA.
// Round-3 proven structure (512 thr, 64 KB LDS, VGPR 128, XCD-paired
// halves) + tile-major AggT (single-segment coalesced 1 KB wave loads).
// ---------------------------------------------------------------------------
__global__ __launch_bounds__(512) void vgemm_kernel(
    const unsigned short* __restrict__ AggT,
    const unsigned short* __restrict__ VfragG,
    float* __restrict__ out, int Ne, int nTiles)
{
    __shared__ short8 ldsV[4096];   // [b][otl][ks][lane], 64 KB
    int half = (blockIdx.x >> 3) & 1;                       // XCD-paired
    int blk  = ((blockIdx.x >> 4) << 3) | (blockIdx.x & 7); // same %8 pair
    int nblk = gridDim.x >> 1;
    int tid  = threadIdx.x;

    for (int i = tid; i < 4096; i += 512) {
        int lane = i & 63, ks = (i >> 6) & 3, otl = (i >> 8) & 3, b = i >> 10;
        int gi = ((b * 8 + half * 4 + otl) * 4 + ks) * 64 + lane;
        ldsV[i] = reinterpret_cast<const short8*>(VfragG)[gi];
    }
    __syncthreads();

    int wave = tid >> 6;
    int lane = tid & 63;
    int quad = lane >> 4, l15 = lane & 15;

    int wgid = blk * 8 + wave;
    int nw   = nblk * 8;

    const short8* AggV = reinterpret_cast<const short8*>(AggT);

    for (int tile = wgid; tile < nTiles; tile += nw) {
        int node = tile * 16 + l15;

        // tile-major: frag (b,ks) for this lane at 16B unit
        //   tile*1024 + b*256 + ks*64 + l15*4 + quad
        const short8* bp = AggV + (size_t)tile * 1024 + l15 * 4 + quad;
        short8 bf[16];
#pragma unroll
        for (int b = 0; b < 4; ++b)
#pragma unroll
            for (int ks = 0; ks < 4; ++ks)
                bf[b * 4 + ks] = bp[b * 256 + ks * 64];

        floatx4 acc[4];
#pragma unroll
        for (int o = 0; o < 4; ++o) acc[o] = (floatx4){0.f, 0.f, 0.f, 0.f};

#pragma unroll
        for (int b = 0; b < 4; ++b)
#pragma unroll
            for (int ks = 0; ks < 4; ++ks)
#pragma unroll
                for (int otl = 0; otl < 4; ++otl)
                    acc[otl] = __builtin_amdgcn_mfma_f32_16x16x32_bf16(
                        ldsV[((b * 4 + otl) * 4 + ks) * 64 + lane],
                        bf[b * 4 + ks], acc[otl], 0, 0, 0);

        if (node < Ne) {
            float* orow = out + (size_t)node * DIM + half * 64;
#pragma unroll
            for (int otl = 0; otl < 4; ++otl) {
                float4 st;
                st.x = acc[otl][0]; st.y = acc[otl][1];
                st.z = acc[otl][2]; st.w = acc[otl][3];
                *reinterpret_cast<float4*>(orow + otl * 16 + quad * 4) = st;
            }
        }
    }
}

// ---------------------------------------------------------------------------
// Fallback (ws too small): round-2 atomic kernel
// ---------------------------------------------------------------------------
__global__ __launch_bounds__(256) void rgcn_main(
    const unsigned short* __restrict__ Hbf,
    const unsigned short* __restrict__ Wfrag,
    const int*   __restrict__ erow,
    const int*   __restrict__ ecol,
    const float* __restrict__ eval,
    float*       __restrict__ out,
    int E, int groups_per_rel, int waves_per_rel)
{
    int wid  = blockIdx.x * 4 + (threadIdx.x >> 6);
    int lane = threadIdx.x & 63;
    int r    = wid & 7;
    int wr   = wid >> 3;
    int quad = lane >> 4;
    int l15  = lane & 15;

    short8 b[8][4];
    {
        const short8* wp = reinterpret_cast<const short8*>(
            Wfrag + (size_t)r * 16384);
#pragma unroll
        for (int ot = 0; ot < 8; ++ot)
#pragma unroll
            for (int ks = 0; ks < 4; ++ks)
                b[ot][ks] = wp[(ot * 4 + ks) * 64 + lane];
    }

    for (int g = wr; g < groups_per_rel; g += waves_per_rel) {
        int ebase = r * E + g * 16;
        int   colv = ecol[ebase + l15];
        int   rowv = erow[ebase + l15];
        float valv = eval[ebase + l15];

        short8 a[4];
        const unsigned short* hp = Hbf + (size_t)colv * DIM + quad * 8;
#pragma unroll
        for (int ks = 0; ks < 4; ++ks)
            a[ks] = *reinterpret_cast<const short8*>(hp + ks * 32);

        floatx4 acc[8];
#pragma unroll
        for (int ot = 0; ot < 8; ++ot) acc[ot] = (floatx4){0.f, 0.f, 0.f, 0.f};
#pragma unroll
        for (int ot = 0; ot < 8; ++ot)
#pragma unroll
            for (int ks = 0; ks < 4; ++ks)
                acc[ot] = __builtin_amdgcn_mfma_f32_16x16x32_bf16(
                    a[ks], b[ot][ks], acc[ot], 0, 0, 0);

        int   row4[4];
        float val4[4];
#pragma unroll
        for (int reg = 0; reg < 4; ++reg) {
            int src  = quad * 4 + reg;
            row4[reg] = __shfl(rowv, src, 64);
            val4[reg] = __shfl(valv, src, 64);
        }
#pragma unroll
        for (int ot = 0; ot < 8; ++ot)
#pragma unroll
            for (int reg = 0; reg < 4; ++reg) {
                float m = acc[ot][reg] * val4[reg];
                atomicAdd(out + (size_t)row4[reg] * DIM + ot * 16 + l15, m);
            }
    }
}

extern "C" void kernel_launch(void* const* d_in, const int* in_sizes, int n_in,
                              void* d_out, int out_size, void* d_ws, size_t ws_size,
                              hipStream_t stream)
{
    const float* H    = (const float*)d_in[0];
    const float* A    = (const float*)d_in[1];
    const float* V    = (const float*)d_in[2];
    const int*   erow = (const int*)d_in[3];
    const int*   ecol = (const int*)d_in[4];
    const float* eval = (const float*)d_in[5];
    float* out = (float*)d_out;

    int Ne    = in_sizes[0] / DIM;   // 100000
    int NEtot = in_sizes[3];         // 1.6M
    int E     = NEtot / NR;          // 200000

    auto al = [](size_t x) { return (x + 255) & ~(size_t)255; };

    int nbuc = (Ne + BROWS - 1) / BROWS;   // 196
    int nTiles = (Ne + 15) / 16;           // 6250 (Ne divisible by 16)

    size_t offHbf    = 0;
    size_t offVfrag  = offHbf    + al((size_t)Ne * DIM * 2);
    size_t offWfrag  = offVfrag  + al((size_t)8192 * 16);
    size_t offAgg    = offWfrag  + al((size_t)16384 * 16);  // sorted1 aliases here
    size_t offRow    = offAgg    + al((size_t)nTiles * 16384);
    size_t offBcnt   = offRow    + al(((size_t)Ne + 2) * 4);
    size_t offSort   = offBcnt   + al((size_t)256 * 4);
    size_t total     = offSort   + al((size_t)NEtot * 8);

    char* ws = (char*)d_ws;
    unsigned short* Hbf    = (unsigned short*)(ws + offHbf);
    unsigned short* VfragG = (unsigned short*)(ws + offVfrag);
    unsigned short* Wfrag  = (unsigned short*)(ws + offWfrag);

    int n8 = Ne * DIM / 8;
    h_to_bf<<<(n8 + 255) / 256, 256, 0, stream>>>(H, Hbf, n8);

    if (ws_size < total) {
        // fallback: atomic-scatter path (round 2)
        build_wfrag<<<64, 256, 0, stream>>>(A, V, Wfrag);
        hipMemsetAsync(d_out, 0, (size_t)Ne * DIM * sizeof(float), stream);
        int blocks = 4096;
        int waves_per_rel = blocks * 4 / NR;
        int groups_per_rel = E / 16;
        rgcn_main<<<blocks, 256, 0, stream>>>(Hbf, Wfrag, erow, ecol, eval, out,
                                              E, groups_per_rel, waves_per_rel);
        return;
    }

    unsigned short* AggT     = (unsigned short*)(ws + offAgg);
    int2*           sorted1  = (int2*)(ws + offAgg);   // alias (dead before AggT)
    int*            rowStart = (int*)(ws + offRow);
    int*            bcnt     = (int*)(ws + offBcnt);
    int2*           sorted   = (int2*)(ws + offSort);

    build_vfrag<<<32, 256, 0, stream>>>(V, VfragG);

    // two-level bucket sort (scan folded into pass 2)
    hipMemsetAsync(bcnt, 0, 256 * 4, stream);
    int sblocks = 1024;
    int chunk   = (NEtot + sblocks - 1) / sblocks;   // 1563
    bucket_scatter<<<sblocks, 256, 0, stream>>>(erow, ecol, eval, bcnt,
                                                sorted1, NEtot, E, chunk);
    bucket_sort<<<nbuc, 1024, 0, stream>>>(sorted1, bcnt, rowStart,
                                           sorted, Ne, nbuc);

    // K_A: 4-basis aggregation, tile-major output layout
    agg_kernel<<<(Ne + 3) / 4, 256, 0, stream>>>(Hbf, rowStart, sorted, A,
                                                 AggT, Ne);

    // K_B: out = AggT @ V via MFMA, V-frags in LDS (two 64-col halves,
    // XCD-paired so both halves of a tile set share one L2)
    vgemm_kernel<<<512, 512, 0, stream>>>(AggT, VfragG, out, Ne, nTiles);
}

// Round 9
// 316.687 us; speedup vs baseline: 1.1322x; 1.0182x over previous
//
#include <hip/hip_runtime.h>

typedef __attribute__((ext_vector_type(8))) short short8;
typedef __attribute__((ext_vector_type(4))) float floatx4;
typedef __attribute__((ext_vector_type(2))) float floatx2;

constexpr int DIM   = 128;   // dim_in == dim_out
constexpr int NB    = 4;     // bases
constexpr int NR    = 8;     // relations
constexpr int BROWS = 512;   // rows per sort bucket
constexpr int BCAP  = 16384; // fixed bucket capacity (mean 8192, +90 sigma)

static __device__ __forceinline__ unsigned short f2bf(float f) {
    unsigned int u = __float_as_uint(f);
    u += 0x7FFFu + ((u >> 16) & 1u);
    return (unsigned short)(u >> 16);
}
static __device__ __forceinline__ float bf_lo(unsigned int h) {
    return __uint_as_float(h << 16);
}
static __device__ __forceinline__ float bf_hi(unsigned int h) {
    return __uint_as_float(h & 0xFFFF0000u);
}

// ---------------------------------------------------------------------------
// Vfrag[b][ot][ks][lane][j] = V[b][k][o], k=ks*32+(lane>>4)*8+j, o=ot*16+(lane&15)
// ---------------------------------------------------------------------------
__global__ __launch_bounds__(256) void build_vfrag(
    const float* __restrict__ V, unsigned short* __restrict__ VfragG)
{
    int idx  = blockIdx.x * 256 + threadIdx.x;   // 0 .. 8191
    int lane = idx & 63;
    int ks   = (idx >> 6) & 3;
    int ot   = (idx >> 8) & 7;
    int b    = idx >> 11;

    int o  = ot * 16 + (lane & 15);
    int kb = ks * 32 + (lane >> 4) * 8;

    short8 v;
#pragma unroll
    for (int j = 0; j < 8; ++j)
        v[j] = (short)f2bf(V[((size_t)b * DIM + kb + j) * DIM + o]);
    *reinterpret_cast<short8*>(VfragG + (size_t)idx * 8) = v;
}

// ---------------------------------------------------------------------------
// W_r fragments (fallback path only)
// ---------------------------------------------------------------------------
__global__ __launch_bounds__(256) void build_wfrag(
    const float* __restrict__ A, const float* __restrict__ V,
    unsigned short* __restrict__ Wfrag)
{
    int idx  = blockIdx.x * 256 + threadIdx.x;   // 0 .. 16383
    int lane = idx & 63;
    int ks   = (idx >> 6) & 3;
    int ot   = (idx >> 8) & 7;
    int r    = idx >> 11;

    int o     = ot * 16 + (lane & 15);
    int kbase = ks * 32 + (lane >> 4) * 8;

    float a0 = A[r * NB + 0], a1 = A[r * NB + 1];
    float a2 = A[r * NB + 2], a3 = A[r * NB + 3];

    short8 v;
#pragma unroll
    for (int j = 0; j < 8; ++j) {
        int k = kbase + j;
        float w = a0 * V[(0 * DIM + k) * DIM + o]
                + a1 * V[(1 * DIM + k) * DIM + o]
                + a2 * V[(2 * DIM + k) * DIM + o]
                + a3 * V[(3 * DIM + k) * DIM + o];
        v[j] = (short)f2bf(w);
    }
    *reinterpret_cast<short8*>(Wfrag + (size_t)idx * 8) = v;
}

// ---------------------------------------------------------------------------
// H (fp32) -> Hbf (bf16), row-major [Ne][128]
// ---------------------------------------------------------------------------
__global__ __launch_bounds__(256) void h_to_bf(
    const float* __restrict__ H, unsigned short* __restrict__ Hbf, int n8)
{
    int i = blockIdx.x * 256 + threadIdx.x;
    if (i >= n8) return;
    const float4* hp = reinterpret_cast<const float4*>(H) + (size_t)i * 2;
    float4 f0 = hp[0];
    float4 f1 = hp[1];
    short8 v;
    v[0] = (short)f2bf(f0.x); v[1] = (short)f2bf(f0.y);
    v[2] = (short)f2bf(f0.z); v[3] = (short)f2bf(f0.w);
    v[4] = (short)f2bf(f1.x); v[5] = (short)f2bf(f1.y);
    v[6] = (short)f2bf(f1.z); v[7] = (short)f2bf(f1.w);
    *reinterpret_cast<short8*>(Hbf + (size_t)i * 8) = v;
}

// ---------------------------------------------------------------------------
// Sort pass 1: scatter edges into fixed-capacity coarse buckets.
// ---------------------------------------------------------------------------
__global__ __launch_bounds__(256) void bucket_scatter(
    const int* __restrict__ erow, const int* __restrict__ ecol,
    const float* __restrict__ eval, int* __restrict__ bcnt,
    int2* __restrict__ sorted1, int n, int E, int chunk)
{
    __shared__ int cnt[256];
    __shared__ int base[256];
    int t = threadIdx.x;
    cnt[t] = 0;
    __syncthreads();

    int s = blockIdx.x * chunk;
    int e = s + chunk; if (e > n) e = n;

    for (int i = s + t; i < e; i += 256)
        atomicAdd(&cnt[erow[i] >> 9], 1);
    __syncthreads();

    int c = cnt[t];
    base[t] = (c > 0) ? atomicAdd(&bcnt[t], c) : 0;
    cnt[t] = 0;
    __syncthreads();

    for (int i = s + t; i < e; i += 256) {
        int row = erow[i];
        int bkt = row >> 9;
        int rank = atomicAdd(&cnt[bkt], 1);
        int r = (int)((unsigned)i / (unsigned)E);
        int2 m;
        m.x = ((row & (BROWS - 1)) << 20) | (r << 17) | ecol[i];
        m.y = __float_as_int(eval[i]);
        sorted1[(size_t)bkt * BCAP + base[bkt] + rank] = m;
    }
}

// ---------------------------------------------------------------------------
// Sort pass 2: one block per bucket; compacts to exact final positions.
// ---------------------------------------------------------------------------
__global__ __launch_bounds__(1024) void bucket_sort(
    const int2* __restrict__ sorted1, const int* __restrict__ bcnt,
    int* __restrict__ rowStart, int2* __restrict__ sorted, int Ne, int nbuc)
{
    __shared__ int hcnt[BROWS];   // per-local-row counts, then rank counters
    __shared__ int hoff[BROWS];   // per-local-row exclusive offsets
    __shared__ int sd[256];       // bucket-count inclusive scan
    int b = blockIdx.x;
    int t = threadIdx.x;

    for (int i = t; i < BROWS; i += 1024) hcnt[i] = 0;

    if (t < 256) sd[t] = (t < nbuc) ? bcnt[t] : 0;
    __syncthreads();
#pragma unroll
    for (int off = 1; off < 256; off <<= 1) {
        int v = (t < 256 && t >= off) ? sd[t - off] : 0;
        __syncthreads();
        if (t < 256) sd[t] += v;
        __syncthreads();
    }
    if (b == 0 && t == nbuc - 1) rowStart[Ne] = sd[t];

    int n  = bcnt[b];
    int bs = sd[b] - n;               // exclusive prefix of this bucket
    const int2* src = sorted1 + (size_t)b * BCAP;

    for (int i = t; i < n; i += 1024)
        atomicAdd(&hcnt[(unsigned)src[i].x >> 20], 1);
    __syncthreads();

    // parallel exclusive scan of the 512 row counts
    if (t < BROWS) hoff[t] = hcnt[t];
    __syncthreads();
#pragma unroll
    for (int off = 1; off < BROWS; off <<= 1) {
        int v = (t < BROWS && t >= off) ? hoff[t - off] : 0;
        __syncthreads();
        if (t < BROWS) hoff[t] += v;
        __syncthreads();
    }
    if (t < BROWS) hoff[t] -= hcnt[t];   // own-element only: no hazard
    __syncthreads();

    int rs = b * BROWS;
    int nr = Ne - rs; if (nr > BROWS) nr = BROWS;
    for (int j = t; j < nr; j += 1024)
        rowStart[rs + j] = bs + hoff[j];

    for (int i = t; i < BROWS; i += 1024) hcnt[i] = 0;
    __syncthreads();

    for (int i = t; i < n; i += 1024) {
        int2 m = src[i];
        int lr = (unsigned)m.x >> 20;
        int pos = bs + hoff[lr] + atomicAdd(&hcnt[lr], 1);
        sorted[pos] = m;
    }
}

// ---------------------------------------------------------------------------
// FUSED K_A + K_B: one persistent 1024-thread block per CU owns one 16-node
// tile at a time. Phase 1: each of 16 waves aggregates one node's K=512 row
// (gather pipeline, round-6 code) and writes it to a 16 KB LDS A-tile in the
// exact AggT tile layout (verified round 5). Phase 2: 8 waves do the tile's
// 128 MFMAs against the full 128 KB V-fragment LDS set and store out rows
// directly. Kills the 102 MB AggT HBM round-trip (~45 us) + one dispatch.
// __launch_bounds__(1024, 4): 4 waves/EU = 1 block/CU -> 128-VGPR cap
// (bare (1024) capped at 64 and spilled in round 2). Peak live ~55 VGPR.
// LDS: 128 KB V + 16 KB A = 144 KB <= 160 KB/CU.
// ---------------------------------------------------------------------------
#define AGG_LOAD8(kk, vv, hh, base)                                          \
    _Pragma("unroll")                                                        \
    for (int u = 0; u < 8; ++u) {                                            \
        int2 m = sorted[(base) + u];                                         \
        kk[u] = __builtin_amdgcn_readfirstlane(m.x);                         \
        vv[u] = __uint_as_float(__builtin_amdgcn_readfirstlane(m.y));        \
    }                                                                        \
    _Pragma("unroll")                                                        \
    for (int u = 0; u < 8; ++u)                                              \
        hh[u] = reinterpret_cast<const unsigned int*>(                       \
            Hbf + (size_t)(kk[u] & 0x1FFFF) * DIM)[lane];

#define AGG_FMA8(kk, vv, hh)                                                 \
    _Pragma("unroll")                                                        \
    for (int u = 0; u < 8; ++u) {                                            \
        float4 a = Af[((unsigned)kk[u] >> 17) & 7];                          \
        floatx2 h; h[0] = bf_lo(hh[u]); h[1] = bf_hi(hh[u]);                 \
        float s0 = vv[u] * a.x, s1 = vv[u] * a.y;                            \
        float s2 = vv[u] * a.z, s3 = vv[u] * a.w;                            \
        acc[0] += (floatx2){s0, s0} * h;                                     \
        acc[1] += (floatx2){s1, s1} * h;                                     \
        acc[2] += (floatx2){s2, s2} * h;                                     \
        acc[3] += (floatx2){s3, s3} * h;                                     \
    }

__global__ __launch_bounds__(1024, 4) void fused_kernel(
    const unsigned short* __restrict__ Hbf,
    const int*  __restrict__ rowStart,
    const int2* __restrict__ sorted,
    const float* __restrict__ Aw,
    const unsigned short* __restrict__ VfragG,
    float* __restrict__ out, int Ne, int nTiles)
{
    __shared__ short8 ldsV[8192];          // full V-frag set, 128 KB
    __shared__ unsigned short ldsA[8192];  // one 16x512 bf16 A-tile, 16 KB

    int tid  = threadIdx.x;
    int wave = tid >> 6;
    int lane = tid & 63;
    int quad = lane >> 4, l15 = lane & 15;

    for (int i = tid; i < 8192; i += 1024)
        ldsV[i] = reinterpret_cast<const short8*>(VfragG)[i];
    // (barrier before first phase-2 use below)

    const float4* Af = reinterpret_cast<const float4*>(Aw);

    // per-lane LDS write slot for the A-tile (AggT tile layout, ushort units):
    // cols {2*lane, 2*lane+1} of basis b for row 'wave':
    //   b*2048 + (lane>>4)*512 + wave*32 + ((lane>>2)&3)*8 + (lane&3)*2
    unsigned short* aw = ldsA + (size_t)wave * 32
                       + (size_t)(lane >> 4) * 512
                       + (size_t)((lane >> 2) & 3) * 8
                       + (size_t)(lane & 3) * 2;

    for (int tile = blockIdx.x; tile < nTiles; tile += gridDim.x) {
        // ---- phase 1: aggregate row (tile*16 + wave) ----
        int node = tile * 16 + wave;
        floatx2 acc[4];
#pragma unroll
        for (int b = 0; b < 4; ++b) acc[b] = (floatx2){0.f, 0.f};

        if (node < Ne) {
            int s = __builtin_amdgcn_readfirstlane(rowStart[node]);
            int e = __builtin_amdgcn_readfirstlane(rowStart[node + 1]);
            int i = s;
            if (i + 8 <= e) {
                int kkA[8], kkB[8];
                float vvA[8], vvB[8];
                unsigned int hhA[8], hhB[8];
                AGG_LOAD8(kkA, vvA, hhA, i); i += 8;
                for (;;) {
                    if (i + 8 <= e) {
                        AGG_LOAD8(kkB, vvB, hhB, i); i += 8;
                        AGG_FMA8(kkA, vvA, hhA);
                    } else { AGG_FMA8(kkA, vvA, hhA); break; }
                    if (i + 8 <= e) {
                        AGG_LOAD8(kkA, vvA, hhA, i); i += 8;
                        AGG_FMA8(kkB, vvB, hhB);
                    } else { AGG_FMA8(kkB, vvB, hhB); break; }
                }
            }
            for (; i < e; ++i) {
                int2 m = sorted[i];
                int k = __builtin_amdgcn_readfirstlane(m.x);
                float v = __uint_as_float(__builtin_amdgcn_readfirstlane(m.y));
                unsigned int hu = reinterpret_cast<const unsigned int*>(
                    Hbf + (size_t)(k & 0x1FFFF) * DIM)[lane];
                float4 a = Af[((unsigned)k >> 17) & 7];
                floatx2 h; h[0] = bf_lo(hu); h[1] = bf_hi(hu);
                float s0 = v * a.x, s1 = v * a.y, s2 = v * a.z, s3 = v * a.w;
                acc[0] += (floatx2){s0, s0} * h;
                acc[1] += (floatx2){s1, s1} * h;
                acc[2] += (floatx2){s2, s2} * h;
                acc[3] += (floatx2){s3, s3} * h;
            }
        }
#pragma unroll
        for (int b = 0; b < 4; ++b) {
            unsigned int pk = (unsigned int)f2bf(acc[b][0])
                            | ((unsigned int)f2bf(acc[b][1]) << 16);
            *reinterpret_cast<unsigned int*>(aw + b * 2048) = pk;
        }
        __syncthreads();   // A-tile complete (and ldsV loaded on first iter)

        // ---- phase 2: waves 0-7 compute output col-block ot = wave ----
        if (wave < 8) {
            int ot = wave;
            const short8* a8 = reinterpret_cast<const short8*>(ldsA);
            floatx4 vacc = (floatx4){0.f, 0.f, 0.f, 0.f};
#pragma unroll
            for (int b = 0; b < 4; ++b)
#pragma unroll
                for (int ks = 0; ks < 4; ++ks)
                    vacc = __builtin_amdgcn_mfma_f32_16x16x32_bf16(
                        ldsV[((b * 8 + ot) * 4 + ks) * 64 + lane],
                        a8[b * 256 + ks * 64 + l15 * 4 + quad],
                        vacc, 0, 0, 0);

            int onode = tile * 16 + l15;
            if (onode < Ne) {
                float4 st;
                st.x = vacc[0]; st.y = vacc[1]; st.z = vacc[2]; st.w = vacc[3];
                *reinterpret_cast<float4*>(
                    out + (size_t)onode * DIM + ot * 16 + quad * 4) = st;
            }
        }
        __syncthreads();   // protect ldsA before next tile overwrites
    }
}

// ---------------------------------------------------------------------------
// Fallback (ws too small): round-2 atomic kernel
// ---------------------------------------------------------------------------
__global__ __launch_bounds__(256) void rgcn_main(
    const unsigned short* __restrict__ Hbf,
    const unsigned short* __restrict__ Wfrag,
    const int*   __restrict__ erow,
    const int*   __restrict__ ecol,
    const float* __restrict__ eval,
    float*       __restrict__ out,
    int E, int groups_per_rel, int waves_per_rel)
{
    int wid  = blockIdx.x * 4 + (threadIdx.x >> 6);
    int lane = threadIdx.x & 63;
    int r    = wid & 7;
    int wr   = wid >> 3;
    int quad = lane >> 4;
    int l15  = lane & 15;

    short8 b[8][4];
    {
        const short8* wp = reinterpret_cast<const short8*>(
            Wfrag + (size_t)r * 16384);
#pragma unroll
        for (int ot = 0; ot < 8; ++ot)
#pragma unroll
            for (int ks = 0; ks < 4; ++ks)
                b[ot][ks] = wp[(ot * 4 + ks) * 64 + lane];
    }

    for (int g = wr; g < groups_per_rel; g += waves_per_rel) {
        int ebase = r * E + g * 16;
        int   colv = ecol[ebase + l15];
        int   rowv = erow[ebase + l15];
        float valv = eval[ebase + l15];

        short8 a[4];
        const unsigned short* hp = Hbf + (size_t)colv * DIM + quad * 8;
#pragma unroll
        for (int ks = 0; ks < 4; ++ks)
            a[ks] = *reinterpret_cast<const short8*>(hp + ks * 32);

        floatx4 acc[8];
#pragma unroll
        for (int ot = 0; ot < 8; ++ot) acc[ot] = (floatx4){0.f, 0.f, 0.f, 0.f};
#pragma unroll
        for (int ot = 0; ot < 8; ++ot)
#pragma unroll
            for (int ks = 0; ks < 4; ++ks)
                acc[ot] = __builtin_amdgcn_mfma_f32_16x16x32_bf16(
                    a[ks], b[ot][ks], acc[ot], 0, 0, 0);

        int   row4[4];
        float val4[4];
#pragma unroll
        for (int reg = 0; reg < 4; ++reg) {
            int src  = quad * 4 + reg;
            row4[reg] = __shfl(rowv, src, 64);
            val4[reg] = __shfl(valv, src, 64);
        }
#pragma unroll
        for (int ot = 0; ot < 8; ++ot)
#pragma unroll
            for (int reg = 0; reg < 4; ++reg) {
                float m = acc[ot][reg] * val4[reg];
                atomicAdd(out + (size_t)row4[reg] * DIM + ot * 16 + l15, m);
            }
    }
}

extern "C" void kernel_launch(void* const* d_in, const int* in_sizes, int n_in,
                              void* d_out, int out_size, void* d_ws, size_t ws_size,
                              hipStream_t stream)
{
    const float* H    = (const float*)d_in[0];
    const float* A    = (const float*)d_in[1];
    const float* V    = (const float*)d_in[2];
    const int*   erow = (const int*)d_in[3];
    const int*   ecol = (const int*)d_in[4];
    const float* eval = (const float*)d_in[5];
    float* out = (float*)d_out;

    int Ne    = in_sizes[0] / DIM;   // 100000
    int NEtot = in_sizes[3];         // 1.6M
    int E     = NEtot / NR;          // 200000

    auto al = [](size_t x) { return (x + 255) & ~(size_t)255; };

    int nbuc = (Ne + BROWS - 1) / BROWS;   // 196
    int nTiles = (Ne + 15) / 16;           // 6250 (Ne divisible by 16)

    size_t offHbf    = 0;
    size_t offVfrag  = offHbf    + al((size_t)Ne * DIM * 2);
    size_t offWfrag  = offVfrag  + al((size_t)8192 * 16);
    size_t offSort1  = offWfrag  + al((size_t)16384 * 16);
    size_t offRow    = offSort1  + al((size_t)nbuc * BCAP * 8);
    size_t offBcnt   = offRow    + al(((size_t)Ne + 2) * 4);
    size_t offSort   = offBcnt   + al((size_t)256 * 4);
    size_t total     = offSort   + al((size_t)NEtot * 8);

    char* ws = (char*)d_ws;
    unsigned short* Hbf    = (unsigned short*)(ws + offHbf);
    unsigned short* VfragG = (unsigned short*)(ws + offVfrag);
    unsigned short* Wfrag  = (unsigned short*)(ws + offWfrag);

    int n8 = Ne * DIM / 8;
    h_to_bf<<<(n8 + 255) / 256, 256, 0, stream>>>(H, Hbf, n8);

    if (ws_size < total) {
        // fallback: atomic-scatter path (round 2)
        build_wfrag<<<64, 256, 0, stream>>>(A, V, Wfrag);
        hipMemsetAsync(d_out, 0, (size_t)Ne * DIM * sizeof(float), stream);
        int blocks = 4096;
        int waves_per_rel = blocks * 4 / NR;
        int groups_per_rel = E / 16;
        rgcn_main<<<blocks, 256, 0, stream>>>(Hbf, Wfrag, erow, ecol, eval, out,
                                              E, groups_per_rel, waves_per_rel);
        return;
    }

    int2*           sorted1  = (int2*)(ws + offSort1);
    int*            rowStart = (int*)(ws + offRow);
    int*            bcnt     = (int*)(ws + offBcnt);
    int2*           sorted   = (int2*)(ws + offSort);

    build_vfrag<<<32, 256, 0, stream>>>(V, VfragG);

    // two-level bucket sort (scan folded into pass 2)
    hipMemsetAsync(bcnt, 0, 256 * 4, stream);
    int sblocks = 1024;
    int chunk   = (NEtot + sblocks - 1) / sblocks;   // 1563
    bucket_scatter<<<sblocks, 256, 0, stream>>>(erow, ecol, eval, bcnt,
                                                sorted1, NEtot, E, chunk);
    bucket_sort<<<nbuc, 1024, 0, stream>>>(sorted1, bcnt, rowStart,
                                           sorted, Ne, nbuc);

    // FUSED aggregation + V-GEMM: persistent, 1 block/CU, AggT never
    // touches HBM.
    fused_kernel<<<256, 1024, 0, stream>>>(Hbf, rowStart, sorted, A,
                                           VfragG, out, Ne, nTiles);
}